// Round 1
// baseline (706.191 us; speedup 1.0000x reference)
//
#include <hip/hip_runtime.h>
#include <stdint.h>
#include <stddef.h>

// ---------------- problem constants ----------------
#define T_TOK  8192        // B*S tokens
#define DIMK   1024        // model dim (K of gemm1)
#define INTERK 1024        // routed expert inter dim
#define NEXP   8
#define SINT   2048        // shared inter dim
#define CAP    17408       // 2*T + 8*128 padding capacity (slot rows)
#define RTMAX  136         // CAP/128 row tiles (worst case)

typedef float  f32x4  __attribute__((ext_vector_type(4)));
typedef short  bf16x8 __attribute__((ext_vector_type(8)));

typedef __attribute__((address_space(1))) const unsigned int gas_u32;
typedef __attribute__((address_space(3))) unsigned int las_u32;

__device__ __forceinline__ void gload16(const void* g, void* l) {
  __builtin_amdgcn_global_load_lds((gas_u32*)g, (las_u32*)l, 16, 0, 0);
}

__device__ __forceinline__ unsigned short f2b(float f) {   // f32 -> bf16 RNE
  unsigned int u = __float_as_uint(f);
  u = (u + 0x7FFFu + ((u >> 16) & 1u)) >> 16;
  return (unsigned short)u;
}
__device__ __forceinline__ float b2f(unsigned short h) {
  return __uint_as_float(((unsigned int)h) << 16);
}

// ---------------- f32 -> bf16 convert ----------------
__global__ __launch_bounds__(256) void cvt_kernel(const float4* __restrict__ in,
                                                  unsigned short* __restrict__ out, int n4) {
  int i = blockIdx.x * 256 + threadIdx.x;
  if (i >= n4) return;
  float4 v = in[i];
  ushort4 o;
  o.x = f2b(v.x); o.y = f2b(v.y); o.z = f2b(v.z); o.w = f2b(v.w);
  *reinterpret_cast<ushort4*>(&out[(size_t)i * 4]) = o;
}

__global__ void init_kernel(int* counts) {
  if (threadIdx.x < NEXP) counts[threadIdx.x] = 0;
}

// ---------------- gate: f32 logits, softmax, top-2 ----------------
__global__ __launch_bounds__(256) void gate_kernel(
    const float* __restrict__ x, const float* __restrict__ gw, const float* __restrict__ gb,
    int* __restrict__ top_i, float* __restrict__ top_w, int* __restrict__ counts) {
  int t    = blockIdx.x * 4 + (threadIdx.x >> 6);
  int lane = threadIdx.x & 63;
  const float* xr = x + (size_t)t * DIMK;
  float acc[NEXP];
#pragma unroll
  for (int e = 0; e < NEXP; ++e) acc[e] = 0.f;
  for (int i = lane; i < DIMK; i += 64) {
    float xv = xr[i];
#pragma unroll
    for (int e = 0; e < NEXP; ++e) acc[e] += xv * gw[e * DIMK + i];
  }
#pragma unroll
  for (int e = 0; e < NEXP; ++e) {
    float v = acc[e];
#pragma unroll
    for (int off = 32; off > 0; off >>= 1) v += __shfl_down(v, off, 64);
    acc[e] = v;
  }
  if (lane == 0) {
    float lg[NEXP];
#pragma unroll
    for (int e = 0; e < NEXP; ++e) lg[e] = acc[e] + gb[e];
    int i0 = 0;
#pragma unroll
    for (int e = 1; e < NEXP; ++e) if (lg[e] > lg[i0]) i0 = e;   // first index wins ties (lax.top_k)
    int i1 = (i0 == 0) ? 1 : 0;
#pragma unroll
    for (int e = 0; e < NEXP; ++e) if (e != i0 && lg[e] > lg[i1]) i1 = e;
    float mx = lg[i0], s = 0.f;
#pragma unroll
    for (int e = 0; e < NEXP; ++e) s += expf(lg[e] - mx);
    top_i[t * 2]     = i0;
    top_i[t * 2 + 1] = i1;
    top_w[t * 2]     = expf(lg[i0] - mx) / s;
    top_w[t * 2 + 1] = expf(lg[i1] - mx) / s;
    atomicAdd(&counts[i0], 1);
    atomicAdd(&counts[i1], 1);
  }
}

// ---------------- scan: padded segment offsets, reset cursors, pad order ----------------
__global__ void scan_kernel(const int* __restrict__ counts, int* __restrict__ poff,
                            int* __restrict__ cursor, int* __restrict__ order) {
  if (threadIdx.x != 0 || blockIdx.x != 0) return;
  int off = 0;
  for (int e = 0; e < NEXP; ++e) {
    poff[e]   = off;
    cursor[e] = 0;
    int c      = counts[e];
    int padded = (c + 127) & ~127;
    for (int p = c; p < padded; ++p) order[off + p] = 0;  // safe dummy token
    off += padded;
  }
  poff[NEXP] = off;
}

// ---------------- build: scatter token ids into expert segments ----------------
__global__ __launch_bounds__(256) void build_kernel(
    const int* __restrict__ top_i, const int* __restrict__ poff,
    int* __restrict__ cursor, int* __restrict__ order, int* __restrict__ pos) {
  int t = blockIdx.x * 256 + threadIdx.x;
  if (t >= T_TOK) return;
#pragma unroll
  for (int k = 0; k < 2; ++k) {
    int e = top_i[t * 2 + k];
    int p = poff[e] + atomicAdd(&cursor[e], 1);
    order[p]       = t;
    pos[t * 2 + k] = p;
  }
}

// ---------------- GEMM1: H = silu(A@W1^T + b1) * (A@W3^T + b3) ----------------
// BM=128, BN=64, BK=64. 4 waves (2x2), wave tile 64x32, dual accumulators.
template <bool INDIRECT>
__global__ __launch_bounds__(256) void gemm1_kernel(
    const unsigned short* __restrict__ A, int lda, const int* __restrict__ order,
    const int* __restrict__ poff,
    const unsigned short* __restrict__ W1, const unsigned short* __restrict__ W3,
    const float* __restrict__ bias1, const float* __restrict__ bias3,
    size_t wstride, int bstride, int K,
    unsigned short* __restrict__ H, int ldh) {
  __shared__ unsigned short As[128 * 64];
  __shared__ unsigned short Bs1[64 * 64];
  __shared__ unsigned short Bs3[64 * 64];

  int rowbase = blockIdx.x * 128;
  int expert  = 0;
  if (poff) {
    if (rowbase >= poff[NEXP]) return;
    while (expert < NEXP - 1 && rowbase >= poff[expert + 1]) ++expert;
  }
  const unsigned short* W1e = W1 + (size_t)expert * wstride;
  const unsigned short* W3e = W3 + (size_t)expert * wstride;

  int tid = threadIdx.x;
  int lane = tid & 63, w = tid >> 6, wr = w >> 1, wc = w & 1;
  int ncolbase = blockIdx.y * 64;

  size_t arow[4];
#pragma unroll
  for (int it = 0; it < 4; ++it) {
    int c = it * 256 + tid;
    int r = c >> 3;
    int gr = INDIRECT ? order[rowbase + r] : (rowbase + r);
    arow[it] = (size_t)gr * lda + (size_t)((c & 7) * 8);
  }
  size_t brow[2];
#pragma unroll
  for (int it = 0; it < 2; ++it) {
    int c = it * 256 + tid;
    int r = c >> 3;
    brow[it] = (size_t)(ncolbase + r) * K + (size_t)((c & 7) * 8);
  }

  f32x4 acc1[4][2], acc3[4][2];
#pragma unroll
  for (int m = 0; m < 4; ++m)
#pragma unroll
    for (int n = 0; n < 2; ++n) {
      acc1[m][n] = f32x4{0.f, 0.f, 0.f, 0.f};
      acc3[m][n] = f32x4{0.f, 0.f, 0.f, 0.f};
    }

  for (int kb = 0; kb < K; kb += 64) {
#pragma unroll
    for (int it = 0; it < 4; ++it)
      gload16(A + arow[it] + kb, &As[(size_t)(it * 256 + tid) * 8]);
#pragma unroll
    for (int it = 0; it < 2; ++it) {
      gload16(W1e + brow[it] + kb, &Bs1[(size_t)(it * 256 + tid) * 8]);
      gload16(W3e + brow[it] + kb, &Bs3[(size_t)(it * 256 + tid) * 8]);
    }
    __syncthreads();
#pragma unroll
    for (int kk = 0; kk < 2; ++kk) {
      int ko = kk * 32 + (lane >> 4) * 8;
      bf16x8 a[4], b1f[2], b3f[2];
#pragma unroll
      for (int m = 0; m < 4; ++m)
        a[m] = *(const bf16x8*)&As[(wr * 64 + m * 16 + (lane & 15)) * 64 + ko];
#pragma unroll
      for (int n = 0; n < 2; ++n) {
        int col = wc * 32 + n * 16 + (lane & 15);
        b1f[n] = *(const bf16x8*)&Bs1[col * 64 + ko];
        b3f[n] = *(const bf16x8*)&Bs3[col * 64 + ko];
      }
#pragma unroll
      for (int m = 0; m < 4; ++m)
#pragma unroll
        for (int n = 0; n < 2; ++n) {
          acc1[m][n] = __builtin_amdgcn_mfma_f32_16x16x32_bf16(a[m], b1f[n], acc1[m][n], 0, 0, 0);
          acc3[m][n] = __builtin_amdgcn_mfma_f32_16x16x32_bf16(a[m], b3f[n], acc3[m][n], 0, 0, 0);
        }
    }
    __syncthreads();
  }

#pragma unroll
  for (int m = 0; m < 4; ++m)
#pragma unroll
    for (int n = 0; n < 2; ++n) {
      int col   = ncolbase + wc * 32 + n * 16 + (lane & 15);
      float bb1 = bias1[bstride * expert + col];
      float bb3 = bias3[bstride * expert + col];
#pragma unroll
      for (int j = 0; j < 4; ++j) {
        int row  = rowbase + wr * 64 + m * 16 + (lane >> 4) * 4 + j;
        float a1 = acc1[m][n][j] + bb1;
        float a3 = acc3[m][n][j] + bb3;
        float hv = (a1 / (1.f + __expf(-a1))) * a3;   // silu(a1)*a3
        H[(size_t)row * ldh + col] = f2b(hv);
      }
    }
}

// ---------------- GEMM2: OUT = A@W2^T + b2 ----------------
// BM=128, BN=128, BK=64. 4 waves (2x2), wave tile 64x64.
template <bool OUTF32>
__global__ __launch_bounds__(256) void gemm2_kernel(
    const unsigned short* __restrict__ A, int lda,
    const int* __restrict__ poff,
    const unsigned short* __restrict__ W2, const float* __restrict__ bias2,
    size_t wstride, int bstride, int K,
    void* __restrict__ outp, int ldo) {
  __shared__ unsigned short As[128 * 64];
  __shared__ unsigned short Bs[128 * 64];

  int rowbase = blockIdx.x * 128;
  int expert  = 0;
  if (poff) {
    if (rowbase >= poff[NEXP]) return;
    while (expert < NEXP - 1 && rowbase >= poff[expert + 1]) ++expert;
  }
  const unsigned short* W2e = W2 + (size_t)expert * wstride;

  int tid = threadIdx.x;
  int lane = tid & 63, w = tid >> 6, wr = w >> 1, wc = w & 1;
  int ncolbase = blockIdx.y * 128;

  f32x4 acc[4][4];
#pragma unroll
  for (int m = 0; m < 4; ++m)
#pragma unroll
    for (int n = 0; n < 4; ++n) acc[m][n] = f32x4{0.f, 0.f, 0.f, 0.f};

  for (int kb = 0; kb < K; kb += 64) {
#pragma unroll
    for (int it = 0; it < 4; ++it) {
      int c  = it * 256 + tid;
      int r  = c >> 3;
      int c8 = (c & 7) * 8;
      gload16(A + (size_t)(rowbase + r) * lda + kb + c8, &As[(size_t)c * 8]);
      gload16(W2e + (size_t)(ncolbase + r) * K + kb + c8, &Bs[(size_t)c * 8]);
    }
    __syncthreads();
#pragma unroll
    for (int kk = 0; kk < 2; ++kk) {
      int ko = kk * 32 + (lane >> 4) * 8;
      bf16x8 a[4], b[4];
#pragma unroll
      for (int m = 0; m < 4; ++m)
        a[m] = *(const bf16x8*)&As[(wr * 64 + m * 16 + (lane & 15)) * 64 + ko];
#pragma unroll
      for (int n = 0; n < 4; ++n)
        b[n] = *(const bf16x8*)&Bs[(wc * 64 + n * 16 + (lane & 15)) * 64 + ko];
#pragma unroll
      for (int m = 0; m < 4; ++m)
#pragma unroll
        for (int n = 0; n < 4; ++n)
          acc[m][n] = __builtin_amdgcn_mfma_f32_16x16x32_bf16(a[m], b[n], acc[m][n], 0, 0, 0);
    }
    __syncthreads();
  }

#pragma unroll
  for (int m = 0; m < 4; ++m)
#pragma unroll
    for (int n = 0; n < 4; ++n) {
      int col  = ncolbase + wc * 64 + n * 16 + (lane & 15);
      float bb = bias2[bstride * expert + col];
#pragma unroll
      for (int j = 0; j < 4; ++j) {
        int row = rowbase + wr * 64 + m * 16 + (lane >> 4) * 4 + j;
        float v = acc[m][n][j] + bb;
        if (OUTF32)
          ((float*)outp)[(size_t)row * ldo + col] = v;
        else
          ((unsigned short*)outp)[(size_t)row * ldo + col] = f2b(v);
      }
    }
}

// ---------------- combine: out += w0*y[p0] + w1*y[p1] ----------------
__global__ __launch_bounds__(256) void combine_kernel(
    float* __restrict__ out, const unsigned short* __restrict__ y,
    const int* __restrict__ pos, const float* __restrict__ tw) {
  size_t idx = (size_t)blockIdx.x * 256 + threadIdx.x;
  if (idx >= (size_t)T_TOK * DIMK) return;
  int t = (int)(idx >> 10);
  int d = (int)(idx & 1023);
  int p0 = pos[t * 2], p1 = pos[t * 2 + 1];
  float w0 = tw[t * 2], w1 = tw[t * 2 + 1];
  out[idx] += w0 * b2f(y[(size_t)p0 * DIMK + d]) + w1 * b2f(y[(size_t)p1 * DIMK + d]);
}

// ---------------- launch ----------------
extern "C" void kernel_launch(void* const* d_in, const int* in_sizes, int n_in,
                              void* d_out, int out_size, void* d_ws, size_t ws_size,
                              hipStream_t stream) {
  const float* x   = (const float*)d_in[0];
  const float* gw  = (const float*)d_in[1];
  const float* gb  = (const float*)d_in[2];
  const float* w1  = (const float*)d_in[3];
  const float* b1  = (const float*)d_in[4];
  const float* w3  = (const float*)d_in[5];
  const float* b3  = (const float*)d_in[6];
  const float* w2  = (const float*)d_in[7];
  const float* b2  = (const float*)d_in[8];
  const float* ws1 = (const float*)d_in[9];
  const float* bs1 = (const float*)d_in[10];
  const float* ws3 = (const float*)d_in[11];
  const float* bs3 = (const float*)d_in[12];
  const float* ws2 = (const float*)d_in[13];
  const float* bs2 = (const float*)d_in[14];
  float* out = (float*)d_out;
  (void)in_sizes; (void)n_in; (void)out_size; (void)ws_size;

  char* p = (char*)d_ws;
  auto alloc = [&](size_t bytes) -> void* {
    void* r = (void*)p;
    p += (bytes + 255) & ~(size_t)255;
    return r;
  };
  unsigned short* xb   = (unsigned short*)alloc((size_t)T_TOK * DIMK * 2);
  unsigned short* w1b  = (unsigned short*)alloc((size_t)NEXP * INTERK * DIMK * 2);
  unsigned short* w3b  = (unsigned short*)alloc((size_t)NEXP * INTERK * DIMK * 2);
  unsigned short* w2b  = (unsigned short*)alloc((size_t)NEXP * DIMK * INTERK * 2);
  unsigned short* ws1b = (unsigned short*)alloc((size_t)SINT * DIMK * 2);
  unsigned short* ws3b = (unsigned short*)alloc((size_t)SINT * DIMK * 2);
  unsigned short* ws2b = (unsigned short*)alloc((size_t)DIMK * SINT * 2);
  unsigned short* h    = (unsigned short*)alloc((size_t)CAP * INTERK * 2);
  unsigned short* yb   = (unsigned short*)alloc((size_t)CAP * DIMK * 2);
  unsigned short* hs   = (unsigned short*)alloc((size_t)T_TOK * SINT * 2);
  int*   top_i  = (int*)alloc((size_t)T_TOK * 2 * 4);
  float* top_w  = (float*)alloc((size_t)T_TOK * 2 * 4);
  int*   pos    = (int*)alloc((size_t)T_TOK * 2 * 4);
  int*   order  = (int*)alloc((size_t)CAP * 4);
  int*   counts = (int*)alloc(64);
  int*   poff   = (int*)alloc(64);
  int*   cursor = (int*)alloc(64);

  init_kernel<<<1, 64, 0, stream>>>(counts);

  auto cvt = [&](const float* src, unsigned short* dst, size_t n) {
    int n4 = (int)(n / 4);
    cvt_kernel<<<(n4 + 255) / 256, 256, 0, stream>>>((const float4*)src, dst, n4);
  };
  cvt(x,   xb,   (size_t)T_TOK * DIMK);
  cvt(w1,  w1b,  (size_t)NEXP * INTERK * DIMK);
  cvt(w3,  w3b,  (size_t)NEXP * INTERK * DIMK);
  cvt(w2,  w2b,  (size_t)NEXP * DIMK * INTERK);
  cvt(ws1, ws1b, (size_t)SINT * DIMK);
  cvt(ws3, ws3b, (size_t)SINT * DIMK);
  cvt(ws2, ws2b, (size_t)DIMK * SINT);

  gate_kernel<<<T_TOK / 4, 256, 0, stream>>>(x, gw, gb, top_i, top_w, counts);
  scan_kernel<<<1, 1, 0, stream>>>(counts, poff, cursor, order);
  build_kernel<<<T_TOK / 256, 256, 0, stream>>>(top_i, poff, cursor, order, pos);

  // routed expert pipeline
  gemm1_kernel<true><<<dim3(RTMAX, INTERK / 64), 256, 0, stream>>>(
      xb, DIMK, order, poff, w1b, w3b, b1, b3,
      (size_t)INTERK * DIMK, INTERK, DIMK, h, INTERK);
  gemm2_kernel<false><<<dim3(RTMAX, DIMK / 128), 256, 0, stream>>>(
      h, INTERK, poff, w2b, b2, (size_t)DIMK * INTERK, DIMK, INTERK,
      (void*)yb, DIMK);

  // shared expert pipeline (writes z straight into d_out)
  gemm1_kernel<false><<<dim3(T_TOK / 128, SINT / 64), 256, 0, stream>>>(
      xb, DIMK, (const int*)nullptr, (const int*)nullptr, ws1b, ws3b, bs1, bs3,
      (size_t)0, 0, DIMK, hs, SINT);
  gemm2_kernel<true><<<dim3(T_TOK / 128, DIMK / 128), 256, 0, stream>>>(
      hs, SINT, (const int*)nullptr, ws2b, bs2, (size_t)0, 0, SINT,
      (void*)out, DIMK);

  // out += routed combine
  combine_kernel<<<(T_TOK * DIMK) / 256, 256, 0, stream>>>(out, yb, pos, top_w);
}

// Round 3
// 473.055 us; speedup vs baseline: 1.4928x; 1.4928x over previous
//
#include <hip/hip_runtime.h>
#include <stdint.h>
#include <stddef.h>

// ---------------- problem constants ----------------
#define T_TOK  8192        // B*S tokens
#define DIMK   1024        // model dim (K of gemm1)
#define INTERK 1024        // routed expert inter dim
#define NEXP   8
#define SINT   2048        // shared inter dim
#define CAP    17408       // 2*T + 8*128 padding capacity (slot rows)
#define RTMAX  136         // CAP/128 row tiles (worst case)

typedef float  f32x4  __attribute__((ext_vector_type(4)));
typedef short  bf16x8 __attribute__((ext_vector_type(8)));

typedef __attribute__((address_space(1))) const unsigned int gas_u32;
typedef __attribute__((address_space(3))) unsigned int las_u32;

__device__ __forceinline__ void gload16(const void* g, void* l) {
  __builtin_amdgcn_global_load_lds((gas_u32*)g, (las_u32*)l, 16, 0, 0);
}

__device__ __forceinline__ unsigned short f2b(float f) {   // f32 -> bf16 RNE
  unsigned int u = __float_as_uint(f);
  u = (u + 0x7FFFu + ((u >> 16) & 1u)) >> 16;
  return (unsigned short)u;
}
__device__ __forceinline__ float b2f(unsigned short h) {
  return __uint_as_float(((unsigned int)h) << 16);
}

// ---------------- f32 -> bf16 convert ----------------
__global__ __launch_bounds__(256) void cvt_kernel(const float4* __restrict__ in,
                                                  unsigned short* __restrict__ out, int n4) {
  int i = blockIdx.x * 256 + threadIdx.x;
  if (i >= n4) return;
  float4 v = in[i];
  ushort4 o;
  o.x = f2b(v.x); o.y = f2b(v.y); o.z = f2b(v.z); o.w = f2b(v.w);
  *reinterpret_cast<ushort4*>(&out[(size_t)i * 4]) = o;
}

// ---------------- gate: f32 logits, softmax, top-2 (NO atomics) ----------------
__global__ __launch_bounds__(256) void gate_kernel(
    const float* __restrict__ x, const float* __restrict__ gw, const float* __restrict__ gb,
    int* __restrict__ top_i, float* __restrict__ top_w) {
  int t    = blockIdx.x * 4 + (threadIdx.x >> 6);
  int lane = threadIdx.x & 63;
  const float* xr = x + (size_t)t * DIMK;
  float acc[NEXP];
#pragma unroll
  for (int e = 0; e < NEXP; ++e) acc[e] = 0.f;
  for (int i = lane; i < DIMK; i += 64) {
    float xv = xr[i];
#pragma unroll
    for (int e = 0; e < NEXP; ++e) acc[e] += xv * gw[e * DIMK + i];
  }
#pragma unroll
  for (int e = 0; e < NEXP; ++e) {
    float v = acc[e];
#pragma unroll
    for (int off = 32; off > 0; off >>= 1) v += __shfl_down(v, off, 64);
    acc[e] = v;
  }
  if (lane == 0) {
    float lg[NEXP];
#pragma unroll
    for (int e = 0; e < NEXP; ++e) lg[e] = acc[e] + gb[e];
    int i0 = 0;
#pragma unroll
    for (int e = 1; e < NEXP; ++e) if (lg[e] > lg[i0]) i0 = e;   // first index wins ties (lax.top_k)
    int i1 = (i0 == 0) ? 1 : 0;
#pragma unroll
    for (int e = 0; e < NEXP; ++e) if (e != i0 && lg[e] > lg[i1]) i1 = e;
    float mx = lg[i0], s = 0.f;
#pragma unroll
    for (int e = 0; e < NEXP; ++e) s += expf(lg[e] - mx);
    top_i[t * 2]     = i0;
    top_i[t * 2 + 1] = i1;
    top_w[t * 2]     = expf(lg[i0] - mx) / s;
    top_w[t * 2 + 1] = expf(lg[i1] - mx) / s;
  }
}

// ---------------- route_build: count + scan + slot-assign, deterministic, no atomics ----
// One block, 512 threads (8 waves). Thread tid owns tokens [tid*16, tid*16+16).
// Wave e prefix-scans expert e's per-thread counts. Then each thread replays its
// tokens assigning consecutive slots. Pad rows point at token 0.
__global__ __launch_bounds__(512) void route_build_kernel(
    const int* __restrict__ top_i, int* __restrict__ order, int* __restrict__ pos,
    int* __restrict__ poff_g) {
  __shared__ int cnt[NEXP][512];
  __shared__ int base[NEXP][512];
  __shared__ int totals[NEXP];
  __shared__ int poff_s[NEXP + 1];
  int tid = threadIdx.x;
  int lane = tid & 63, w = tid >> 6;
  const int t0 = tid * 16;

  // phase 1: private histogram (branch-unrolled: no runtime-indexed array -> no scratch)
  int c[NEXP];
#pragma unroll
  for (int e = 0; e < NEXP; ++e) c[e] = 0;
  for (int j = 0; j < 16; ++j) {
    int e0 = top_i[(t0 + j) * 2];
    int e1 = top_i[(t0 + j) * 2 + 1];
#pragma unroll
    for (int e = 0; e < NEXP; ++e) c[e] += (e0 == e) + (e1 == e);
  }
#pragma unroll
  for (int e = 0; e < NEXP; ++e) cnt[e][tid] = c[e];
  __syncthreads();

  // phase 2: wave w scans expert w over 512 thread-counts (8 chunks of 64)
  {
    int running = 0;
    for (int ch = 0; ch < 8; ++ch) {
      int v = cnt[w][ch * 64 + lane];
      int incl = v;
#pragma unroll
      for (int off = 1; off < 64; off <<= 1) {
        int u = __shfl_up(incl, off, 64);
        if (lane >= off) incl += u;
      }
      base[w][ch * 64 + lane] = running + incl - v;
      running += __shfl(incl, 63, 64);
    }
    if (lane == 0) totals[w] = running;
  }
  __syncthreads();

  // phase 3: padded offsets
  if (tid == 0) {
    int off = 0;
#pragma unroll
    for (int e = 0; e < NEXP; ++e) {
      poff_s[e] = off;
      off += (totals[e] + 127) & ~127;
    }
    poff_s[NEXP] = off;
#pragma unroll
    for (int e = 0; e <= NEXP; ++e) poff_g[e] = poff_s[e];
  }
  __syncthreads();

  // phase 4: replay, assign slots
  int cur[NEXP];
#pragma unroll
  for (int e = 0; e < NEXP; ++e) cur[e] = poff_s[e] + base[e][tid];
  for (int j = 0; j < 16; ++j) {
    int t = t0 + j;
#pragma unroll
    for (int k = 0; k < 2; ++k) {
      int ei = top_i[t * 2 + k];
      int p = 0;
#pragma unroll
      for (int e = 0; e < NEXP; ++e)
        if (ei == e) { p = cur[e]; cur[e] = p + 1; }
      order[p]       = t;
      pos[t * 2 + k] = p;
    }
  }

  // phase 5: fill pad slots with token 0 (values never used in combine)
#pragma unroll
  for (int e = 0; e < NEXP; ++e) {
    int s = poff_s[e] + totals[e], en = poff_s[e + 1];
    for (int i = s + tid; i < en; i += 512) order[i] = 0;
  }
}

// ---------------- GEMM1: H = silu(A@W1^T + b1) * (A@W3^T + b3) ----------------
// BM=128, BN=64, BK=64. 4 waves (2x2), wave tile 64x32, dual accumulators.
template <bool INDIRECT>
__global__ __launch_bounds__(256) void gemm1_kernel(
    const unsigned short* __restrict__ A, int lda, const int* __restrict__ order,
    const int* __restrict__ poff,
    const unsigned short* __restrict__ W1, const unsigned short* __restrict__ W3,
    const float* __restrict__ bias1, const float* __restrict__ bias3,
    size_t wstride, int bstride, int K,
    unsigned short* __restrict__ H, int ldh) {
  __shared__ unsigned short As[128 * 64];
  __shared__ unsigned short Bs1[64 * 64];
  __shared__ unsigned short Bs3[64 * 64];

  int rowbase = blockIdx.x * 128;
  int expert  = 0;
  if (poff) {
    if (rowbase >= poff[NEXP]) return;
    while (expert < NEXP - 1 && rowbase >= poff[expert + 1]) ++expert;
  }
  const unsigned short* W1e = W1 + (size_t)expert * wstride;
  const unsigned short* W3e = W3 + (size_t)expert * wstride;

  int tid = threadIdx.x;
  int lane = tid & 63, w = tid >> 6, wr = w >> 1, wc = w & 1;
  int ncolbase = blockIdx.y * 64;

  size_t arow[4];
#pragma unroll
  for (int it = 0; it < 4; ++it) {
    int c = it * 256 + tid;
    int r = c >> 3;
    int gr = INDIRECT ? order[rowbase + r] : (rowbase + r);
    arow[it] = (size_t)gr * lda + (size_t)((c & 7) * 8);
  }
  size_t brow[2];
#pragma unroll
  for (int it = 0; it < 2; ++it) {
    int c = it * 256 + tid;
    int r = c >> 3;
    brow[it] = (size_t)(ncolbase + r) * K + (size_t)((c & 7) * 8);
  }

  f32x4 acc1[4][2], acc3[4][2];
#pragma unroll
  for (int m = 0; m < 4; ++m)
#pragma unroll
    for (int n = 0; n < 2; ++n) {
      acc1[m][n] = f32x4{0.f, 0.f, 0.f, 0.f};
      acc3[m][n] = f32x4{0.f, 0.f, 0.f, 0.f};
    }

  for (int kb = 0; kb < K; kb += 64) {
#pragma unroll
    for (int it = 0; it < 4; ++it)
      gload16(A + arow[it] + kb, &As[(size_t)(it * 256 + tid) * 8]);
#pragma unroll
    for (int it = 0; it < 2; ++it) {
      gload16(W1e + brow[it] + kb, &Bs1[(size_t)(it * 256 + tid) * 8]);
      gload16(W3e + brow[it] + kb, &Bs3[(size_t)(it * 256 + tid) * 8]);
    }
    __syncthreads();
#pragma unroll
    for (int kk = 0; kk < 2; ++kk) {
      int ko = kk * 32 + (lane >> 4) * 8;
      bf16x8 a[4], b1f[2], b3f[2];
#pragma unroll
      for (int m = 0; m < 4; ++m)
        a[m] = *(const bf16x8*)&As[(wr * 64 + m * 16 + (lane & 15)) * 64 + ko];
#pragma unroll
      for (int n = 0; n < 2; ++n) {
        int col = wc * 32 + n * 16 + (lane & 15);
        b1f[n] = *(const bf16x8*)&Bs1[col * 64 + ko];
        b3f[n] = *(const bf16x8*)&Bs3[col * 64 + ko];
      }
#pragma unroll
      for (int m = 0; m < 4; ++m)
#pragma unroll
        for (int n = 0; n < 2; ++n) {
          acc1[m][n] = __builtin_amdgcn_mfma_f32_16x16x32_bf16(a[m], b1f[n], acc1[m][n], 0, 0, 0);
          acc3[m][n] = __builtin_amdgcn_mfma_f32_16x16x32_bf16(a[m], b3f[n], acc3[m][n], 0, 0, 0);
        }
    }
    __syncthreads();
  }

#pragma unroll
  for (int m = 0; m < 4; ++m)
#pragma unroll
    for (int n = 0; n < 2; ++n) {
      int col   = ncolbase + wc * 32 + n * 16 + (lane & 15);
      float bb1 = bias1[bstride * expert + col];
      float bb3 = bias3[bstride * expert + col];
#pragma unroll
      for (int j = 0; j < 4; ++j) {
        int row  = rowbase + wr * 64 + m * 16 + (lane >> 4) * 4 + j;
        float a1 = acc1[m][n][j] + bb1;
        float a3 = acc3[m][n][j] + bb3;
        float hv = (a1 / (1.f + __expf(-a1))) * a3;   // silu(a1)*a3
        H[(size_t)row * ldh + col] = f2b(hv);
      }
    }
}

// ---------------- GEMM2: OUT = A@W2^T + b2 ----------------
// BM=128, BN=128, BK=64. 4 waves (2x2), wave tile 64x64.
template <bool OUTF32>
__global__ __launch_bounds__(256) void gemm2_kernel(
    const unsigned short* __restrict__ A, int lda,
    const int* __restrict__ poff,
    const unsigned short* __restrict__ W2, const float* __restrict__ bias2,
    size_t wstride, int bstride, int K,
    void* __restrict__ outp, int ldo) {
  __shared__ unsigned short As[128 * 64];
  __shared__ unsigned short Bs[128 * 64];

  int rowbase = blockIdx.x * 128;
  int expert  = 0;
  if (poff) {
    if (rowbase >= poff[NEXP]) return;
    while (expert < NEXP - 1 && rowbase >= poff[expert + 1]) ++expert;
  }
  const unsigned short* W2e = W2 + (size_t)expert * wstride;

  int tid = threadIdx.x;
  int lane = tid & 63, w = tid >> 6, wr = w >> 1, wc = w & 1;
  int ncolbase = blockIdx.y * 128;

  f32x4 acc[4][4];
#pragma unroll
  for (int m = 0; m < 4; ++m)
#pragma unroll
    for (int n = 0; n < 4; ++n) acc[m][n] = f32x4{0.f, 0.f, 0.f, 0.f};

  for (int kb = 0; kb < K; kb += 64) {
#pragma unroll
    for (int it = 0; it < 4; ++it) {
      int c  = it * 256 + tid;
      int r  = c >> 3;
      int c8 = (c & 7) * 8;
      gload16(A + (size_t)(rowbase + r) * lda + kb + c8, &As[(size_t)c * 8]);
      gload16(W2e + (size_t)(ncolbase + r) * K + kb + c8, &Bs[(size_t)c * 8]);
    }
    __syncthreads();
#pragma unroll
    for (int kk = 0; kk < 2; ++kk) {
      int ko = kk * 32 + (lane >> 4) * 8;
      bf16x8 a[4], b[4];
#pragma unroll
      for (int m = 0; m < 4; ++m)
        a[m] = *(const bf16x8*)&As[(wr * 64 + m * 16 + (lane & 15)) * 64 + ko];
#pragma unroll
      for (int n = 0; n < 4; ++n)
        b[n] = *(const bf16x8*)&Bs[(wc * 64 + n * 16 + (lane & 15)) * 64 + ko];
#pragma unroll
      for (int m = 0; m < 4; ++m)
#pragma unroll
        for (int n = 0; n < 4; ++n)
          acc[m][n] = __builtin_amdgcn_mfma_f32_16x16x32_bf16(a[m], b[n], acc[m][n], 0, 0, 0);
    }
    __syncthreads();
  }

#pragma unroll
  for (int m = 0; m < 4; ++m)
#pragma unroll
    for (int n = 0; n < 4; ++n) {
      int col  = ncolbase + wc * 64 + n * 16 + (lane & 15);
      float bb = bias2[bstride * expert + col];
#pragma unroll
      for (int j = 0; j < 4; ++j) {
        int row = rowbase + wr * 64 + m * 16 + (lane >> 4) * 4 + j;
        float v = acc[m][n][j] + bb;
        if (OUTF32)
          ((float*)outp)[(size_t)row * ldo + col] = v;
        else
          ((unsigned short*)outp)[(size_t)row * ldo + col] = f2b(v);
      }
    }
}

// ---------------- combine: out += w0*y[p0] + w1*y[p1] ----------------
__global__ __launch_bounds__(256) void combine_kernel(
    float* __restrict__ out, const unsigned short* __restrict__ y,
    const int* __restrict__ pos, const float* __restrict__ tw) {
  size_t idx = (size_t)blockIdx.x * 256 + threadIdx.x;
  if (idx >= (size_t)T_TOK * DIMK) return;
  int t = (int)(idx >> 10);
  int d = (int)(idx & 1023);
  int p0 = pos[t * 2], p1 = pos[t * 2 + 1];
  float w0 = tw[t * 2], w1 = tw[t * 2 + 1];
  out[idx] += w0 * b2f(y[(size_t)p0 * DIMK + d]) + w1 * b2f(y[(size_t)p1 * DIMK + d]);
}

// ---------------- launch ----------------
extern "C" void kernel_launch(void* const* d_in, const int* in_sizes, int n_in,
                              void* d_out, int out_size, void* d_ws, size_t ws_size,
                              hipStream_t stream) {
  const float* x   = (const float*)d_in[0];
  const float* gw  = (const float*)d_in[1];
  const float* gb  = (const float*)d_in[2];
  const float* w1  = (const float*)d_in[3];
  const float* b1  = (const float*)d_in[4];
  const float* w3  = (const float*)d_in[5];
  const float* b3  = (const float*)d_in[6];
  const float* w2  = (const float*)d_in[7];
  const float* b2  = (const float*)d_in[8];
  const float* ws1 = (const float*)d_in[9];
  const float* bs1 = (const float*)d_in[10];
  const float* ws3 = (const float*)d_in[11];
  const float* bs3 = (const float*)d_in[12];
  const float* ws2 = (const float*)d_in[13];
  const float* bs2 = (const float*)d_in[14];
  float* out = (float*)d_out;
  (void)in_sizes; (void)n_in; (void)out_size; (void)ws_size;

  char* p = (char*)d_ws;
  auto alloc = [&](size_t bytes) -> void* {
    void* r = (void*)p;
    p += (bytes + 255) & ~(size_t)255;
    return r;
  };
  unsigned short* xb   = (unsigned short*)alloc((size_t)T_TOK * DIMK * 2);
  unsigned short* w1b  = (unsigned short*)alloc((size_t)NEXP * INTERK * DIMK * 2);
  unsigned short* w3b  = (unsigned short*)alloc((size_t)NEXP * INTERK * DIMK * 2);
  unsigned short* w2b  = (unsigned short*)alloc((size_t)NEXP * DIMK * INTERK * 2);
  unsigned short* ws1b = (unsigned short*)alloc((size_t)SINT * DIMK * 2);
  unsigned short* ws3b = (unsigned short*)alloc((size_t)SINT * DIMK * 2);
  unsigned short* ws2b = (unsigned short*)alloc((size_t)DIMK * SINT * 2);
  unsigned short* h    = (unsigned short*)alloc((size_t)CAP * INTERK * 2);
  unsigned short* yb   = (unsigned short*)alloc((size_t)CAP * DIMK * 2);
  unsigned short* hs   = (unsigned short*)alloc((size_t)T_TOK * SINT * 2);
  int*   top_i  = (int*)alloc((size_t)T_TOK * 2 * 4);
  float* top_w  = (float*)alloc((size_t)T_TOK * 2 * 4);
  int*   pos    = (int*)alloc((size_t)T_TOK * 2 * 4);
  int*   order  = (int*)alloc((size_t)CAP * 4);
  int*   poff   = (int*)alloc(64);

  auto cvt = [&](const float* src, unsigned short* dst, size_t n) {
    int n4 = (int)(n / 4);
    cvt_kernel<<<(n4 + 255) / 256, 256, 0, stream>>>((const float4*)src, dst, n4);
  };
  cvt(x,   xb,   (size_t)T_TOK * DIMK);
  cvt(w1,  w1b,  (size_t)NEXP * INTERK * DIMK);
  cvt(w3,  w3b,  (size_t)NEXP * INTERK * DIMK);
  cvt(w2,  w2b,  (size_t)NEXP * DIMK * INTERK);
  cvt(ws1, ws1b, (size_t)SINT * DIMK);
  cvt(ws3, ws3b, (size_t)SINT * DIMK);
  cvt(ws2, ws2b, (size_t)DIMK * SINT);

  gate_kernel<<<T_TOK / 4, 256, 0, stream>>>(x, gw, gb, top_i, top_w);
  route_build_kernel<<<1, 512, 0, stream>>>(top_i, order, pos, poff);

  // routed expert pipeline
  gemm1_kernel<true><<<dim3(RTMAX, INTERK / 64), 256, 0, stream>>>(
      xb, DIMK, order, poff, w1b, w3b, b1, b3,
      (size_t)INTERK * DIMK, INTERK, DIMK, h, INTERK);
  gemm2_kernel<false><<<dim3(RTMAX, DIMK / 128), 256, 0, stream>>>(
      h, INTERK, poff, w2b, b2, (size_t)DIMK * INTERK, DIMK, INTERK,
      (void*)yb, DIMK);

  // shared expert pipeline (writes z straight into d_out)
  gemm1_kernel<false><<<dim3(T_TOK / 128, SINT / 64), 256, 0, stream>>>(
      xb, DIMK, (const int*)nullptr, (const int*)nullptr, ws1b, ws3b, bs1, bs3,
      (size_t)0, 0, DIMK, hs, SINT);
  gemm2_kernel<true><<<dim3(T_TOK / 128, DIMK / 128), 256, 0, stream>>>(
      hs, SINT, (const int*)nullptr, ws2b, bs2, (size_t)0, 0, SINT,
      (void*)out, DIMK);

  // out += routed combine
  combine_kernel<<<(T_TOK * DIMK) / 256, 256, 0, stream>>>(out, yb, pos, top_w);
}

// Round 6
// 421.912 us; speedup vs baseline: 1.6738x; 1.1212x over previous
//
#include <hip/hip_runtime.h>
#include <stdint.h>
#include <stddef.h>

// ---------------- problem constants ----------------
#define T_TOK  8192        // B*S tokens
#define DIMK   1024        // model dim
#define INTERK 1024        // routed expert inter dim
#define NEXP   8
#define SINT   2048        // shared inter dim
#define CAP    17408       // 2*T + 8*128 padding capacity (slot rows)
#define RTMAX  136         // CAP/128 row tiles (worst case)

typedef float  f32x4  __attribute__((ext_vector_type(4)));
typedef short  bf16x8 __attribute__((ext_vector_type(8)));

typedef __attribute__((address_space(1))) const unsigned int gas_u32;
typedef __attribute__((address_space(3))) unsigned int las_u32;

__device__ __forceinline__ void gload16(const void* g, void* l) {
  __builtin_amdgcn_global_load_lds((gas_u32*)g, (las_u32*)l, 16, 0, 0);
}

__device__ __forceinline__ unsigned short f2b(float f) {   // f32 -> bf16 RNE
  unsigned int u = __float_as_uint(f);
  u = (u + 0x7FFFu + ((u >> 16) & 1u)) >> 16;
  return (unsigned short)u;
}
__device__ __forceinline__ float b2f(unsigned short h) {
  return __uint_as_float(((unsigned int)h) << 16);
}

// ---------------- f32 -> bf16 convert (plain) ----------------
__global__ __launch_bounds__(256) void cvt_kernel(const float4* __restrict__ in,
                                                  unsigned short* __restrict__ out, int n4) {
  int i = blockIdx.x * 256 + threadIdx.x;
  if (i >= n4) return;
  float4 v = in[i];
  ushort4 o;
  o.x = f2b(v.x); o.y = f2b(v.y); o.z = f2b(v.z); o.w = f2b(v.w);
  *reinterpret_cast<ushort4*>(&out[(size_t)i * 4]) = o;
}

// ---------------- f32 -> bf16 convert, interleaving w1/w3 rows in 16-row groups ----
// dst (per expert, 2*ROWS rows): rows [32g..32g+15] = w1 rows [16g..16g+15],
//                                rows [32g+16..32g+31] = w3 rows [16g..16g+15].
// K4 = K/4 float4 chunks per row.
template <int ROWS_PER_E, int K4>
__global__ __launch_bounds__(256) void cvt_w13_kernel(
    const float4* __restrict__ w1, const float4* __restrict__ w3,
    unsigned short* __restrict__ out, int n /* = E*ROWS_PER_E*K4 */) {
  int idx = blockIdx.x * 256 + threadIdx.x;
  int is3 = idx >= n;
  int i = is3 ? idx - n : idx;
  if (i >= n) return;
  int r  = i / K4;           // global source row (e*ROWS_PER_E + rr)
  int kc = i - r * K4;
  int e  = r / ROWS_PER_E;
  int rr = r - e * ROWS_PER_E;
  int g  = rr >> 4;
  size_t dst_r = (size_t)e * (2 * ROWS_PER_E) + g * 32 + (is3 ? 16 : 0) + (rr & 15);
  float4 v = (is3 ? w3 : w1)[i];
  ushort4 o;
  o.x = f2b(v.x); o.y = f2b(v.y); o.z = f2b(v.z); o.w = f2b(v.w);
  *reinterpret_cast<ushort4*>(&out[(dst_r * K4 + kc) * 4]) = o;
}

// ---------------- gate: f32 logits, softmax, top-2 (no atomics) ----------------
__global__ __launch_bounds__(256) void gate_kernel(
    const float* __restrict__ x, const float* __restrict__ gw, const float* __restrict__ gb,
    int* __restrict__ top_i, float* __restrict__ top_w) {
  int t    = blockIdx.x * 4 + (threadIdx.x >> 6);
  int lane = threadIdx.x & 63;
  const float* xr = x + (size_t)t * DIMK;
  float acc[NEXP];
#pragma unroll
  for (int e = 0; e < NEXP; ++e) acc[e] = 0.f;
  for (int i = lane; i < DIMK; i += 64) {
    float xv = xr[i];
#pragma unroll
    for (int e = 0; e < NEXP; ++e) acc[e] += xv * gw[e * DIMK + i];
  }
#pragma unroll
  for (int e = 0; e < NEXP; ++e) {
    float v = acc[e];
#pragma unroll
    for (int off = 32; off > 0; off >>= 1) v += __shfl_down(v, off, 64);
    acc[e] = v;
  }
  if (lane == 0) {
    float lg[NEXP];
#pragma unroll
    for (int e = 0; e < NEXP; ++e) lg[e] = acc[e] + gb[e];
    int i0 = 0;
#pragma unroll
    for (int e = 1; e < NEXP; ++e) if (lg[e] > lg[i0]) i0 = e;   // first index wins ties
    int i1 = (i0 == 0) ? 1 : 0;
#pragma unroll
    for (int e = 0; e < NEXP; ++e) if (e != i0 && lg[e] > lg[i1]) i1 = e;
    float mx = lg[i0], s = 0.f;
#pragma unroll
    for (int e = 0; e < NEXP; ++e) s += expf(lg[e] - mx);
    top_i[t * 2]     = i0;
    top_i[t * 2 + 1] = i1;
    top_w[t * 2]     = expf(lg[i0] - mx) / s;
    top_w[t * 2 + 1] = expf(lg[i1] - mx) / s;
  }
}

// ---------------- route_build: count + scan + slot-assign, deterministic ----------
__global__ __launch_bounds__(512) void route_build_kernel(
    const int* __restrict__ top_i, int* __restrict__ order, int* __restrict__ pos,
    int* __restrict__ poff_g) {
  __shared__ int cnt[NEXP][512];
  __shared__ int base[NEXP][512];
  __shared__ int totals[NEXP];
  __shared__ int poff_s[NEXP + 1];
  int tid = threadIdx.x;
  int lane = tid & 63, w = tid >> 6;
  const int t0 = tid * 16;

  int c[NEXP];
#pragma unroll
  for (int e = 0; e < NEXP; ++e) c[e] = 0;
  for (int j = 0; j < 16; ++j) {
    int e0 = top_i[(t0 + j) * 2];
    int e1 = top_i[(t0 + j) * 2 + 1];
#pragma unroll
    for (int e = 0; e < NEXP; ++e) c[e] += (e0 == e) + (e1 == e);
  }
#pragma unroll
  for (int e = 0; e < NEXP; ++e) cnt[e][tid] = c[e];
  __syncthreads();

  {
    int running = 0;
    for (int ch = 0; ch < 8; ++ch) {
      int v = cnt[w][ch * 64 + lane];
      int incl = v;
#pragma unroll
      for (int off = 1; off < 64; off <<= 1) {
        int u = __shfl_up(incl, off, 64);
        if (lane >= off) incl += u;
      }
      base[w][ch * 64 + lane] = running + incl - v;
      running += __shfl(incl, 63, 64);
    }
    if (lane == 0) totals[w] = running;
  }
  __syncthreads();

  if (tid == 0) {
    int off = 0;
#pragma unroll
    for (int e = 0; e < NEXP; ++e) {
      poff_s[e] = off;
      off += (totals[e] + 127) & ~127;
    }
    poff_s[NEXP] = off;
#pragma unroll
    for (int e = 0; e <= NEXP; ++e) poff_g[e] = poff_s[e];
  }
  __syncthreads();

  int cur[NEXP];
#pragma unroll
  for (int e = 0; e < NEXP; ++e) cur[e] = poff_s[e] + base[e][tid];
  for (int j = 0; j < 16; ++j) {
    int t = t0 + j;
#pragma unroll
    for (int k = 0; k < 2; ++k) {
      int ei = top_i[t * 2 + k];
      int p = 0;
#pragma unroll
      for (int e = 0; e < NEXP; ++e)
        if (ei == e) { p = cur[e]; cur[e] = p + 1; }
      order[p]       = t;
      pos[t * 2 + k] = p;
    }
  }

#pragma unroll
  for (int e = 0; e < NEXP; ++e) {
    int s = poff_s[e] + totals[e], en = poff_s[e + 1];
    for (int i = s + tid; i < en; i += 512) order[i] = 0;
  }
}

// ---------------- unified 128x128 GEMM (m97 structure + XOR-swizzled LDS) ------
// EPI 0: paired swiglu epilogue (interleaved w1/w3 B) -> bf16 H, real N = gridN*64
// EPI 1: bias -> bf16 out
// EPI 2: bias -> f32 out
template <bool EXPERTS, bool GATHER, int EPI>
__global__ __launch_bounds__(256) void gemm_kernel(
    const unsigned short* __restrict__ A, int lda,
    const int* __restrict__ order, const int* __restrict__ poff,
    const unsigned short* __restrict__ B,          // row-major [N][K], per-expert wstride
    const float* __restrict__ bias1, const float* __restrict__ bias3,
    size_t wstride, int bstride, int K,
    void* __restrict__ outp, int ldo) {
  __shared__ unsigned short As[128 * 64];
  __shared__ unsigned short Bs[128 * 64];

  int rowbase = blockIdx.x * 128;
  int expert  = 0;
  if (EXPERTS) {
    if (rowbase >= poff[NEXP]) return;
    while (expert < NEXP - 1 && rowbase >= poff[expert + 1]) ++expert;
  }
  const unsigned short* Be = B + (size_t)expert * wstride;

  int tid = threadIdx.x;
  int lane = tid & 63, w = tid >> 6, wr = w >> 1, wc = w & 1;
  int ncolbase = blockIdx.y * 128;

  // staging addresses; global source chunk pre-swizzled: sub_src = (c&7) ^ (r&7)
  size_t arow[4], brow[4];
#pragma unroll
  for (int it = 0; it < 4; ++it) {
    int c = it * 256 + tid;
    int r = c >> 3;
    int sub = (c & 7) ^ (r & 7);
    int gr = GATHER ? order[rowbase + r] : (rowbase + r);
    arow[it] = (size_t)gr * lda + (size_t)(sub * 8);
    brow[it] = (size_t)(ncolbase + r) * K + (size_t)(sub * 8);
  }

  f32x4 acc[4][4];
#pragma unroll
  for (int m = 0; m < 4; ++m)
#pragma unroll
    for (int n = 0; n < 4; ++n) acc[m][n] = f32x4{0.f, 0.f, 0.f, 0.f};

  for (int kb = 0; kb < K; kb += 64) {
#pragma unroll
    for (int it = 0; it < 4; ++it) {
      int c = it * 256 + tid;
      gload16(A + arow[it] + kb, &As[(size_t)c * 8]);
      gload16(Be + brow[it] + kb, &Bs[(size_t)c * 8]);
    }
    __syncthreads();
#pragma unroll
    for (int kk = 0; kk < 2; ++kk) {
      bf16x8 a[4], b[4];
#pragma unroll
      for (int m = 0; m < 4; ++m) {
        int ra = wr * 64 + m * 16 + (lane & 15);
        int sa = (kk * 4 + (lane >> 4)) ^ (ra & 7);
        a[m] = *(const bf16x8*)&As[ra * 64 + sa * 8];
      }
#pragma unroll
      for (int n = 0; n < 4; ++n) {
        int rb = wc * 64 + n * 16 + (lane & 15);
        int sb = (kk * 4 + (lane >> 4)) ^ (rb & 7);
        b[n] = *(const bf16x8*)&Bs[rb * 64 + sb * 8];
      }
#pragma unroll
      for (int m = 0; m < 4; ++m)
#pragma unroll
        for (int n = 0; n < 4; ++n)
          acc[m][n] = __builtin_amdgcn_mfma_f32_16x16x32_bf16(a[m], b[n], acc[m][n], 0, 0, 0);
    }
    __syncthreads();
  }

  if (EPI == 0) {
    // interleaved pairs: n even = w1 fragment, n odd = w3 fragment
#pragma unroll
    for (int m = 0; m < 4; ++m)
#pragma unroll
      for (int np = 0; np < 2; ++np) {
        int realcol = (ncolbase >> 1) + wc * 32 + np * 16 + (lane & 15);
        float bb1 = bias1[bstride * expert + realcol];
        float bb3 = bias3[bstride * expert + realcol];
#pragma unroll
        for (int j = 0; j < 4; ++j) {
          int row  = rowbase + wr * 64 + m * 16 + (lane >> 4) * 4 + j;
          float a1 = acc[m][2 * np][j] + bb1;
          float a3 = acc[m][2 * np + 1][j] + bb3;
          float hv = (a1 / (1.f + __expf(-a1))) * a3;   // silu(a1)*a3
          ((unsigned short*)outp)[(size_t)row * ldo + realcol] = f2b(hv);
        }
      }
  } else {
#pragma unroll
    for (int m = 0; m < 4; ++m)
#pragma unroll
      for (int n = 0; n < 4; ++n) {
        int col  = ncolbase + wc * 64 + n * 16 + (lane & 15);
        float bb = bias1[bstride * expert + col];
#pragma unroll
        for (int j = 0; j < 4; ++j) {
          int row = rowbase + wr * 64 + m * 16 + (lane >> 4) * 4 + j;
          float v = acc[m][n][j] + bb;
          if (EPI == 2)
            ((float*)outp)[(size_t)row * ldo + col] = v;
          else
            ((unsigned short*)outp)[(size_t)row * ldo + col] = f2b(v);
        }
      }
  }
}

// ---------------- combine: out += w0*y[p0] + w1*y[p1] ----------------
__global__ __launch_bounds__(256) void combine_kernel(
    float* __restrict__ out, const unsigned short* __restrict__ y,
    const int* __restrict__ pos, const float* __restrict__ tw) {
  size_t idx = (size_t)blockIdx.x * 256 + threadIdx.x;
  if (idx >= (size_t)T_TOK * DIMK) return;
  int t = (int)(idx >> 10);
  int d = (int)(idx & 1023);
  int p0 = pos[t * 2], p1 = pos[t * 2 + 1];
  float w0 = tw[t * 2], w1 = tw[t * 2 + 1];
  out[idx] += w0 * b2f(y[(size_t)p0 * DIMK + d]) + w1 * b2f(y[(size_t)p1 * DIMK + d]);
}

// ---------------- launch ----------------
extern "C" void kernel_launch(void* const* d_in, const int* in_sizes, int n_in,
                              void* d_out, int out_size, void* d_ws, size_t ws_size,
                              hipStream_t stream) {
  const float* x   = (const float*)d_in[0];
  const float* gw  = (const float*)d_in[1];
  const float* gb  = (const float*)d_in[2];
  const float* w1  = (const float*)d_in[3];
  const float* b1  = (const float*)d_in[4];
  const float* w3  = (const float*)d_in[5];
  const float* b3  = (const float*)d_in[6];
  const float* w2  = (const float*)d_in[7];
  const float* b2  = (const float*)d_in[8];
  const float* ws1 = (const float*)d_in[9];
  const float* bs1 = (const float*)d_in[10];
  const float* ws3 = (const float*)d_in[11];
  const float* bs3 = (const float*)d_in[12];
  const float* ws2 = (const float*)d_in[13];
  const float* bs2 = (const float*)d_in[14];
  float* out = (float*)d_out;
  (void)in_sizes; (void)n_in; (void)out_size; (void)ws_size;

  char* p = (char*)d_ws;
  auto alloc = [&](size_t bytes) -> void* {
    void* r = (void*)p;
    p += (bytes + 255) & ~(size_t)255;
    return r;
  };
  unsigned short* xb    = (unsigned short*)alloc((size_t)T_TOK * DIMK * 2);
  unsigned short* w13r  = (unsigned short*)alloc((size_t)NEXP * 2 * INTERK * DIMK * 2);
  unsigned short* w2b   = (unsigned short*)alloc((size_t)NEXP * DIMK * INTERK * 2);
  unsigned short* w13s  = (unsigned short*)alloc((size_t)2 * SINT * DIMK * 2);
  unsigned short* ws2b  = (unsigned short*)alloc((size_t)DIMK * SINT * 2);
  unsigned short* h     = (unsigned short*)alloc((size_t)CAP * INTERK * 2);
  unsigned short* yb    = (unsigned short*)alloc((size_t)CAP * DIMK * 2);
  unsigned short* hs    = (unsigned short*)alloc((size_t)T_TOK * SINT * 2);
  int*   top_i  = (int*)alloc((size_t)T_TOK * 2 * 4);
  float* top_w  = (float*)alloc((size_t)T_TOK * 2 * 4);
  int*   pos    = (int*)alloc((size_t)T_TOK * 2 * 4);
  int*   order  = (int*)alloc((size_t)CAP * 4);
  int*   poff   = (int*)alloc(64);

  auto cvt = [&](const float* src, unsigned short* dst, size_t n) {
    int n4 = (int)(n / 4);
    cvt_kernel<<<(n4 + 255) / 256, 256, 0, stream>>>((const float4*)src, dst, n4);
  };
  cvt(x,   xb,   (size_t)T_TOK * DIMK);
  cvt(w2,  w2b,  (size_t)NEXP * DIMK * INTERK);
  cvt(ws2, ws2b, (size_t)DIMK * SINT);

  {  // routed w1/w3 -> interleaved w13r
    int n = NEXP * INTERK * (DIMK / 4);
    cvt_w13_kernel<INTERK, DIMK / 4><<<(2 * n + 255) / 256, 256, 0, stream>>>(
        (const float4*)w1, (const float4*)w3, w13r, n);
  }
  {  // shared ws1/ws3 -> interleaved w13s
    int n = SINT * (DIMK / 4);
    cvt_w13_kernel<SINT, DIMK / 4><<<(2 * n + 255) / 256, 256, 0, stream>>>(
        (const float4*)ws1, (const float4*)ws3, w13s, n);
  }

  gate_kernel<<<T_TOK / 4, 256, 0, stream>>>(x, gw, gb, top_i, top_w);
  route_build_kernel<<<1, 512, 0, stream>>>(top_i, order, pos, poff);

  // routed expert pipeline
  gemm_kernel<true, true, 0><<<dim3(RTMAX, (2 * INTERK) / 128), 256, 0, stream>>>(
      xb, DIMK, order, poff, w13r, b1, b3,
      (size_t)2 * INTERK * DIMK, INTERK, DIMK, h, INTERK);
  gemm_kernel<true, false, 1><<<dim3(RTMAX, DIMK / 128), 256, 0, stream>>>(
      h, INTERK, (const int*)nullptr, poff, w2b, b2, (const float*)nullptr,
      (size_t)DIMK * INTERK, DIMK, INTERK, (void*)yb, DIMK);

  // shared expert pipeline (writes z straight into d_out)
  gemm_kernel<false, false, 0><<<dim3(T_TOK / 128, (2 * SINT) / 128), 256, 0, stream>>>(
      xb, DIMK, (const int*)nullptr, (const int*)nullptr, w13s, bs1, bs3,
      (size_t)0, 0, DIMK, hs, SINT);
  gemm_kernel<false, false, 2><<<dim3(T_TOK / 128, DIMK / 128), 256, 0, stream>>>(
      hs, SINT, (const int*)nullptr, (const int*)nullptr, ws2b, bs2, (const float*)nullptr,
      (size_t)0, 0, SINT, (void*)out, DIMK);

  // out += routed combine
  combine_kernel<<<(T_TOK * DIMK) / 256, 256, 0, stream>>>(out, yb, pos, top_w);
}

// Round 7
// 398.615 us; speedup vs baseline: 1.7716x; 1.0584x over previous
//
#include <hip/hip_runtime.h>
#include <stdint.h>
#include <stddef.h>

// ---------------- problem constants ----------------
#define T_TOK  8192        // B*S tokens
#define DIMK   1024        // model dim
#define INTERK 1024        // routed expert inter dim
#define NEXP   8
#define SINT   2048        // shared inter dim
#define CAP    18432       // 2*T + 8*256 padding capacity (slot rows, 256-aligned)
#define RT256  72          // CAP/256 row tiles (worst case)

typedef float  f32x4  __attribute__((ext_vector_type(4)));
typedef short  bf16x8 __attribute__((ext_vector_type(8)));

typedef __attribute__((address_space(1))) const unsigned int gas_u32;
typedef __attribute__((address_space(3))) unsigned int las_u32;

__device__ __forceinline__ void gload16(const void* g, void* l) {
  __builtin_amdgcn_global_load_lds((gas_u32*)g, (las_u32*)l, 16, 0, 0);
}

__device__ __forceinline__ unsigned short f2b(float f) {   // f32 -> bf16 RNE
  unsigned int u = __float_as_uint(f);
  u = (u + 0x7FFFu + ((u >> 16) & 1u)) >> 16;
  return (unsigned short)u;
}
__device__ __forceinline__ float b2f(unsigned short h) {
  return __uint_as_float(((unsigned int)h) << 16);
}

// raw barrier with compile-time memory fences (no vmcnt/lgkmcnt drain)
__device__ __forceinline__ void barrier_nodrain() {
  asm volatile("" ::: "memory");
  __builtin_amdgcn_s_barrier();
  asm volatile("" ::: "memory");
}

// ---------------- f32 -> bf16 convert (plain) ----------------
__global__ __launch_bounds__(256) void cvt_kernel(const float4* __restrict__ in,
                                                  unsigned short* __restrict__ out, int n4) {
  int i = blockIdx.x * 256 + threadIdx.x;
  if (i >= n4) return;
  float4 v = in[i];
  ushort4 o;
  o.x = f2b(v.x); o.y = f2b(v.y); o.z = f2b(v.z); o.w = f2b(v.w);
  *reinterpret_cast<ushort4*>(&out[(size_t)i * 4]) = o;
}

// ---------------- f32 -> bf16 convert, interleaving w1/w3 rows in 16-row groups ----
template <int ROWS_PER_E, int K4>
__global__ __launch_bounds__(256) void cvt_w13_kernel(
    const float4* __restrict__ w1, const float4* __restrict__ w3,
    unsigned short* __restrict__ out, int n /* = E*ROWS_PER_E*K4 */) {
  int idx = blockIdx.x * 256 + threadIdx.x;
  int is3 = idx >= n;
  int i = is3 ? idx - n : idx;
  if (i >= n) return;
  int r  = i / K4;
  int kc = i - r * K4;
  int e  = r / ROWS_PER_E;
  int rr = r - e * ROWS_PER_E;
  int g  = rr >> 4;
  size_t dst_r = (size_t)e * (2 * ROWS_PER_E) + g * 32 + (is3 ? 16 : 0) + (rr & 15);
  float4 v = (is3 ? w3 : w1)[i];
  ushort4 o;
  o.x = f2b(v.x); o.y = f2b(v.y); o.z = f2b(v.z); o.w = f2b(v.w);
  *reinterpret_cast<ushort4*>(&out[(dst_r * K4 + kc) * 4]) = o;
}

// ---------------- gate: f32 logits, softmax, top-2 (no atomics) ----------------
__global__ __launch_bounds__(256) void gate_kernel(
    const float* __restrict__ x, const float* __restrict__ gw, const float* __restrict__ gb,
    int* __restrict__ top_i, float* __restrict__ top_w) {
  int t    = blockIdx.x * 4 + (threadIdx.x >> 6);
  int lane = threadIdx.x & 63;
  const float* xr = x + (size_t)t * DIMK;
  float acc[NEXP];
#pragma unroll
  for (int e = 0; e < NEXP; ++e) acc[e] = 0.f;
  for (int i = lane; i < DIMK; i += 64) {
    float xv = xr[i];
#pragma unroll
    for (int e = 0; e < NEXP; ++e) acc[e] += xv * gw[e * DIMK + i];
  }
#pragma unroll
  for (int e = 0; e < NEXP; ++e) {
    float v = acc[e];
#pragma unroll
    for (int off = 32; off > 0; off >>= 1) v += __shfl_down(v, off, 64);
    acc[e] = v;
  }
  if (lane == 0) {
    float lg[NEXP];
#pragma unroll
    for (int e = 0; e < NEXP; ++e) lg[e] = acc[e] + gb[e];
    int i0 = 0;
#pragma unroll
    for (int e = 1; e < NEXP; ++e) if (lg[e] > lg[i0]) i0 = e;   // first index wins ties
    int i1 = (i0 == 0) ? 1 : 0;
#pragma unroll
    for (int e = 0; e < NEXP; ++e) if (e != i0 && lg[e] > lg[i1]) i1 = e;
    float mx = lg[i0], s = 0.f;
#pragma unroll
    for (int e = 0; e < NEXP; ++e) s += expf(lg[e] - mx);
    top_i[t * 2]     = i0;
    top_i[t * 2 + 1] = i1;
    top_w[t * 2]     = expf(lg[i0] - mx) / s;
    top_w[t * 2 + 1] = expf(lg[i1] - mx) / s;
  }
}

// ---------------- route_build: count + scan + slot-assign, deterministic ----------
// pads each expert segment to a multiple of 256 (BM of the 8-wave GEMM).
__global__ __launch_bounds__(512) void route_build_kernel(
    const int* __restrict__ top_i, int* __restrict__ order, int* __restrict__ pos,
    int* __restrict__ poff_g) {
  __shared__ int cnt[NEXP][512];
  __shared__ int base[NEXP][512];
  __shared__ int totals[NEXP];
  __shared__ int poff_s[NEXP + 1];
  int tid = threadIdx.x;
  int lane = tid & 63, w = tid >> 6;
  const int t0 = tid * 16;

  int c[NEXP];
#pragma unroll
  for (int e = 0; e < NEXP; ++e) c[e] = 0;
  for (int j = 0; j < 16; ++j) {
    int e0 = top_i[(t0 + j) * 2];
    int e1 = top_i[(t0 + j) * 2 + 1];
#pragma unroll
    for (int e = 0; e < NEXP; ++e) c[e] += (e0 == e) + (e1 == e);
  }
#pragma unroll
  for (int e = 0; e < NEXP; ++e) cnt[e][tid] = c[e];
  __syncthreads();

  {
    int running = 0;
    for (int ch = 0; ch < 8; ++ch) {
      int v = cnt[w][ch * 64 + lane];
      int incl = v;
#pragma unroll
      for (int off = 1; off < 64; off <<= 1) {
        int u = __shfl_up(incl, off, 64);
        if (lane >= off) incl += u;
      }
      base[w][ch * 64 + lane] = running + incl - v;
      running += __shfl(incl, 63, 64);
    }
    if (lane == 0) totals[w] = running;
  }
  __syncthreads();

  if (tid == 0) {
    int off = 0;
#pragma unroll
    for (int e = 0; e < NEXP; ++e) {
      poff_s[e] = off;
      off += (totals[e] + 255) & ~255;
    }
    poff_s[NEXP] = off;
#pragma unroll
    for (int e = 0; e <= NEXP; ++e) poff_g[e] = poff_s[e];
  }
  __syncthreads();

  int cur[NEXP];
#pragma unroll
  for (int e = 0; e < NEXP; ++e) cur[e] = poff_s[e] + base[e][tid];
  for (int j = 0; j < 16; ++j) {
    int t = t0 + j;
#pragma unroll
    for (int k = 0; k < 2; ++k) {
      int ei = top_i[t * 2 + k];
      int p = 0;
#pragma unroll
      for (int e = 0; e < NEXP; ++e)
        if (ei == e) { p = cur[e]; cur[e] = p + 1; }
      order[p]       = t;
      pos[t * 2 + k] = p;
    }
  }

#pragma unroll
  for (int e = 0; e < NEXP; ++e) {
    int s = poff_s[e] + totals[e], en = poff_s[e + 1];
    for (int i = s + tid; i < en; i += 512) order[i] = 0;
  }
}

// ---------------- pipelined GEMM: BM=256, BN=128, BK=64, 512 thr (8 waves 4x2) ----
// Double-buffered LDS (96 KB), counted vmcnt(6), raw barriers (no drain), T5 setprio.
// EPI 0: paired swiglu epilogue (interleaved w1/w3 B) -> bf16 H, real cols = BN/2
// EPI 1: bias -> bf16 out;  EPI 2: bias -> f32 out
#define A_ELE  16384   // 256*64 elements per A buffer
#define B_ELE  8192    // 128*64 elements per B buffer
template <bool EXPERTS, bool GATHER, int EPI>
__global__ __launch_bounds__(512) void gemm256_kernel(
    const unsigned short* __restrict__ A, int lda,
    const int* __restrict__ order, const int* __restrict__ poff,
    const unsigned short* __restrict__ B,          // row-major [N][K], per-expert wstride
    const float* __restrict__ bias1, const float* __restrict__ bias3,
    size_t wstride, int bstride, int K,
    void* __restrict__ outp, int ldo) {
  __shared__ unsigned short lds[2 * A_ELE + 2 * B_ELE];   // 96 KiB

  int rowbase = blockIdx.x * 256;
  int expert  = 0;
  if (EXPERTS) {
    if (rowbase >= poff[NEXP]) return;
    while (expert < NEXP - 1 && rowbase >= poff[expert + 1]) ++expert;
  }
  const unsigned short* Be = B + (size_t)expert * wstride;

  int tid = threadIdx.x;
  int lane = tid & 63, wid = tid >> 6;
  int wr = wid >> 1, wc = wid & 1;            // 4 x 2 wave grid: 64 rows x 64 cols each
  int ncolbase = blockIdx.y * 128;

  // staging addresses (element offsets); source chunk pre-swizzled: sub = (g&7)^(row&7)
  size_t aoff[4], boff[2];
#pragma unroll
  for (int l = 0; l < 4; ++l) {
    int g = l * 512 + tid;
    int r = g >> 3;
    int sub = (g & 7) ^ (r & 7);
    int gr = GATHER ? order[rowbase + r] : (rowbase + r);
    aoff[l] = (size_t)gr * lda + (size_t)(sub * 8);
  }
#pragma unroll
  for (int l = 0; l < 2; ++l) {
    int g = l * 512 + tid;
    int r = g >> 3;
    int sub = (g & 7) ^ (r & 7);
    boff[l] = (size_t)(ncolbase + r) * K + (size_t)(sub * 8);
  }

  f32x4 acc[4][4];
#pragma unroll
  for (int m = 0; m < 4; ++m)
#pragma unroll
    for (int n = 0; n < 4; ++n) acc[m][n] = f32x4{0.f, 0.f, 0.f, 0.f};

  const int NT = K >> 6;

  // ---- prologue: stage tile 0 into buffer 0 (6 loads/thread) ----
#pragma unroll
  for (int l = 0; l < 4; ++l)
    gload16(A + aoff[l], &lds[(size_t)(l * 512 + tid) * 8]);
#pragma unroll
  for (int l = 0; l < 2; ++l)
    gload16(Be + boff[l], &lds[2 * A_ELE + (size_t)(l * 512 + tid) * 8]);

  for (int t = 0; t < NT; ++t) {
    int cur = t & 1;
    // stage tile t+1 into the other buffer (freed by tile t-1's end barrier)
    if (t + 1 < NT) {
      int kb = (t + 1) << 6;
      int nxt = cur ^ 1;
#pragma unroll
      for (int l = 0; l < 4; ++l)
        gload16(A + aoff[l] + kb, &lds[(size_t)nxt * A_ELE + (size_t)(l * 512 + tid) * 8]);
#pragma unroll
      for (int l = 0; l < 2; ++l)
        gload16(Be + boff[l] + kb, &lds[2 * A_ELE + (size_t)nxt * B_ELE + (size_t)(l * 512 + tid) * 8]);
      asm volatile("s_waitcnt vmcnt(6)" ::: "memory");   // tile t landed; t+1 in flight
    } else {
      asm volatile("s_waitcnt vmcnt(0)" ::: "memory");   // last tile: drain
    }
    barrier_nodrain();   // all waves' tile-t staging visible

    const unsigned short* Ab = &lds[(size_t)cur * A_ELE];
    const unsigned short* Bb = &lds[2 * A_ELE + (size_t)cur * B_ELE];
    __builtin_amdgcn_s_setprio(1);
#pragma unroll
    for (int kk = 0; kk < 2; ++kk) {
      bf16x8 a[4], b[4];
#pragma unroll
      for (int m = 0; m < 4; ++m) {
        int ra = wr * 64 + m * 16 + (lane & 15);
        int sa = (kk * 4 + (lane >> 4)) ^ (ra & 7);
        a[m] = *(const bf16x8*)&Ab[ra * 64 + sa * 8];
      }
#pragma unroll
      for (int n = 0; n < 4; ++n) {
        int rb = wc * 64 + n * 16 + (lane & 15);
        int sb = (kk * 4 + (lane >> 4)) ^ (rb & 7);
        b[n] = *(const bf16x8*)&Bb[rb * 64 + sb * 8];
      }
#pragma unroll
      for (int m = 0; m < 4; ++m)
#pragma unroll
        for (int n = 0; n < 4; ++n)
          acc[m][n] = __builtin_amdgcn_mfma_f32_16x16x32_bf16(a[m], b[n], acc[m][n], 0, 0, 0);
    }
    __builtin_amdgcn_s_setprio(0);
    asm volatile("s_waitcnt lgkmcnt(0)" ::: "memory");   // my LDS reads complete
    barrier_nodrain();   // protect buf[cur^1... (t+2 target) from re-stage before all reads done
  }

  if (EPI == 0) {
    // interleaved pairs: n even = w1 fragment, n odd = w3 fragment; real cols = BN/2
#pragma unroll
    for (int m = 0; m < 4; ++m)
#pragma unroll
      for (int np = 0; np < 2; ++np) {
        int realcol = (ncolbase >> 1) + wc * 32 + np * 16 + (lane & 15);
        float bb1 = bias1[bstride * expert + realcol];
        float bb3 = bias3[bstride * expert + realcol];
#pragma unroll
        for (int j = 0; j < 4; ++j) {
          int row  = rowbase + wr * 64 + m * 16 + (lane >> 4) * 4 + j;
          float a1 = acc[m][2 * np][j] + bb1;
          float a3 = acc[m][2 * np + 1][j] + bb3;
          float hv = (a1 / (1.f + __expf(-a1))) * a3;   // silu(a1)*a3
          ((unsigned short*)outp)[(size_t)row * ldo + realcol] = f2b(hv);
        }
      }
  } else {
#pragma unroll
    for (int m = 0; m < 4; ++m)
#pragma unroll
      for (int n = 0; n < 4; ++n) {
        int col  = ncolbase + wc * 64 + n * 16 + (lane & 15);
        float bb = bias1[bstride * expert + col];
#pragma unroll
        for (int j = 0; j < 4; ++j) {
          int row = rowbase + wr * 64 + m * 16 + (lane >> 4) * 4 + j;
          float v = acc[m][n][j] + bb;
          if (EPI == 2)
            ((float*)outp)[(size_t)row * ldo + col] = v;
          else
            ((unsigned short*)outp)[(size_t)row * ldo + col] = f2b(v);
        }
      }
  }
}

// ---------------- combine: out += w0*y[p0] + w1*y[p1] ----------------
__global__ __launch_bounds__(256) void combine_kernel(
    float* __restrict__ out, const unsigned short* __restrict__ y,
    const int* __restrict__ pos, const float* __restrict__ tw) {
  size_t idx = (size_t)blockIdx.x * 256 + threadIdx.x;
  if (idx >= (size_t)T_TOK * DIMK) return;
  int t = (int)(idx >> 10);
  int d = (int)(idx & 1023);
  int p0 = pos[t * 2], p1 = pos[t * 2 + 1];
  float w0 = tw[t * 2], w1 = tw[t * 2 + 1];
  out[idx] += w0 * b2f(y[(size_t)p0 * DIMK + d]) + w1 * b2f(y[(size_t)p1 * DIMK + d]);
}

// ---------------- launch ----------------
extern "C" void kernel_launch(void* const* d_in, const int* in_sizes, int n_in,
                              void* d_out, int out_size, void* d_ws, size_t ws_size,
                              hipStream_t stream) {
  const float* x   = (const float*)d_in[0];
  const float* gw  = (const float*)d_in[1];
  const float* gb  = (const float*)d_in[2];
  const float* w1  = (const float*)d_in[3];
  const float* b1  = (const float*)d_in[4];
  const float* w3  = (const float*)d_in[5];
  const float* b3  = (const float*)d_in[6];
  const float* w2  = (const float*)d_in[7];
  const float* b2  = (const float*)d_in[8];
  const float* ws1 = (const float*)d_in[9];
  const float* bs1 = (const float*)d_in[10];
  const float* ws3 = (const float*)d_in[11];
  const float* bs3 = (const float*)d_in[12];
  const float* ws2 = (const float*)d_in[13];
  const float* bs2 = (const float*)d_in[14];
  float* out = (float*)d_out;
  (void)in_sizes; (void)n_in; (void)out_size; (void)ws_size;

  char* p = (char*)d_ws;
  auto alloc = [&](size_t bytes) -> void* {
    void* r = (void*)p;
    p += (bytes + 255) & ~(size_t)255;
    return r;
  };
  unsigned short* xb    = (unsigned short*)alloc((size_t)T_TOK * DIMK * 2);
  unsigned short* w13r  = (unsigned short*)alloc((size_t)NEXP * 2 * INTERK * DIMK * 2);
  unsigned short* w2b   = (unsigned short*)alloc((size_t)NEXP * DIMK * INTERK * 2);
  unsigned short* w13s  = (unsigned short*)alloc((size_t)2 * SINT * DIMK * 2);
  unsigned short* ws2b  = (unsigned short*)alloc((size_t)DIMK * SINT * 2);
  unsigned short* h     = (unsigned short*)alloc((size_t)CAP * INTERK * 2);
  unsigned short* yb    = (unsigned short*)alloc((size_t)CAP * DIMK * 2);
  unsigned short* hs    = (unsigned short*)alloc((size_t)T_TOK * SINT * 2);
  int*   top_i  = (int*)alloc((size_t)T_TOK * 2 * 4);
  float* top_w  = (float*)alloc((size_t)T_TOK * 2 * 4);
  int*   pos    = (int*)alloc((size_t)T_TOK * 2 * 4);
  int*   order  = (int*)alloc((size_t)CAP * 4);
  int*   poff   = (int*)alloc(64);

  auto cvt = [&](const float* src, unsigned short* dst, size_t n) {
    int n4 = (int)(n / 4);
    cvt_kernel<<<(n4 + 255) / 256, 256, 0, stream>>>((const float4*)src, dst, n4);
  };
  cvt(x,   xb,   (size_t)T_TOK * DIMK);
  cvt(w2,  w2b,  (size_t)NEXP * DIMK * INTERK);
  cvt(ws2, ws2b, (size_t)DIMK * SINT);

  {  // routed w1/w3 -> interleaved w13r
    int n = NEXP * INTERK * (DIMK / 4);
    cvt_w13_kernel<INTERK, DIMK / 4><<<(2 * n + 255) / 256, 256, 0, stream>>>(
        (const float4*)w1, (const float4*)w3, w13r, n);
  }
  {  // shared ws1/ws3 -> interleaved w13s
    int n = SINT * (DIMK / 4);
    cvt_w13_kernel<SINT, DIMK / 4><<<(2 * n + 255) / 256, 256, 0, stream>>>(
        (const float4*)ws1, (const float4*)ws3, w13s, n);
  }

  gate_kernel<<<T_TOK / 4, 256, 0, stream>>>(x, gw, gb, top_i, top_w);
  route_build_kernel<<<1, 512, 0, stream>>>(top_i, order, pos, poff);

  // routed expert pipeline
  gemm256_kernel<true, true, 0><<<dim3(RT256, (2 * INTERK) / 128), 512, 0, stream>>>(
      xb, DIMK, order, poff, w13r, b1, b3,
      (size_t)2 * INTERK * DIMK, INTERK, DIMK, h, INTERK);
  gemm256_kernel<true, false, 1><<<dim3(RT256, DIMK / 128), 512, 0, stream>>>(
      h, INTERK, (const int*)nullptr, poff, w2b, b2, (const float*)nullptr,
      (size_t)DIMK * INTERK, DIMK, INTERK, (void*)yb, DIMK);

  // shared expert pipeline (writes z straight into d_out)
  gemm256_kernel<false, false, 0><<<dim3(T_TOK / 256, (2 * SINT) / 128), 512, 0, stream>>>(
      xb, DIMK, (const int*)nullptr, (const int*)nullptr, w13s, bs1, bs3,
      (size_t)0, 0, DIMK, hs, SINT);
  gemm256_kernel<false, false, 2><<<dim3(T_TOK / 256, DIMK / 128), 512, 0, stream>>>(
      hs, SINT, (const int*)nullptr, (const int*)nullptr, ws2b, bs2, (const float*)nullptr,
      (size_t)0, 0, SINT, (void*)out, DIMK);

  // out += routed combine
  combine_kernel<<<(T_TOK * DIMK) / 256, 256, 0, stream>>>(out, yb, pos, top_w);
}

// Round 8
// 397.832 us; speedup vs baseline: 1.7751x; 1.0020x over previous
//
#include <hip/hip_runtime.h>
#include <stdint.h>
#include <stddef.h>

// ---------------- problem constants ----------------
#define T_TOK  8192        // B*S tokens
#define DIMK   1024        // model dim
#define INTERK 1024        // routed expert inter dim
#define NEXP   8
#define SINT   2048        // shared inter dim
#define CAP    18432       // 2*T + 8*256 padding capacity (slot rows, 256-aligned)
#define RT256  72          // CAP/256 row tiles (worst case)

typedef float  f32x4  __attribute__((ext_vector_type(4)));
typedef short  bf16x8 __attribute__((ext_vector_type(8)));

typedef __attribute__((address_space(1))) const unsigned int gas_u32;
typedef __attribute__((address_space(3))) unsigned int las_u32;

__device__ __forceinline__ void gload16(const void* g, void* l) {
  __builtin_amdgcn_global_load_lds((gas_u32*)g, (las_u32*)l, 16, 0, 0);
}

__device__ __forceinline__ unsigned short f2b(float f) {   // f32 -> bf16 RNE
  unsigned int u = __float_as_uint(f);
  u = (u + 0x7FFFu + ((u >> 16) & 1u)) >> 16;
  return (unsigned short)u;
}
__device__ __forceinline__ float b2f(unsigned short h) {
  return __uint_as_float(((unsigned int)h) << 16);
}

// raw barrier with compile-time memory fences (no vmcnt/lgkmcnt drain)
__device__ __forceinline__ void barrier_nodrain() {
  asm volatile("" ::: "memory");
  __builtin_amdgcn_s_barrier();
  asm volatile("" ::: "memory");
}

// ---------------- f32 -> bf16 convert (plain) ----------------
__global__ __launch_bounds__(256) void cvt_kernel(const float4* __restrict__ in,
                                                  unsigned short* __restrict__ out, int n4) {
  int i = blockIdx.x * 256 + threadIdx.x;
  if (i >= n4) return;
  float4 v = in[i];
  ushort4 o;
  o.x = f2b(v.x); o.y = f2b(v.y); o.z = f2b(v.z); o.w = f2b(v.w);
  *reinterpret_cast<ushort4*>(&out[(size_t)i * 4]) = o;
}

// ---------------- f32 -> bf16 convert, interleaving w1/w3 rows in 16-row groups ----
template <int ROWS_PER_E, int K4>
__global__ __launch_bounds__(256) void cvt_w13_kernel(
    const float4* __restrict__ w1, const float4* __restrict__ w3,
    unsigned short* __restrict__ out, int n /* = E*ROWS_PER_E*K4 */) {
  int idx = blockIdx.x * 256 + threadIdx.x;
  int is3 = idx >= n;
  int i = is3 ? idx - n : idx;
  if (i >= n) return;
  int r  = i / K4;
  int kc = i - r * K4;
  int e  = r / ROWS_PER_E;
  int rr = r - e * ROWS_PER_E;
  int g  = rr >> 4;
  size_t dst_r = (size_t)e * (2 * ROWS_PER_E) + g * 32 + (is3 ? 16 : 0) + (rr & 15);
  float4 v = (is3 ? w3 : w1)[i];
  ushort4 o;
  o.x = f2b(v.x); o.y = f2b(v.y); o.z = f2b(v.z); o.w = f2b(v.w);
  *reinterpret_cast<ushort4*>(&out[(dst_r * K4 + kc) * 4]) = o;
}

// ---------------- gate: f32 logits, softmax, top-2 (no atomics) ----------------
__global__ __launch_bounds__(256) void gate_kernel(
    const float* __restrict__ x, const float* __restrict__ gw, const float* __restrict__ gb,
    int* __restrict__ top_i, float* __restrict__ top_w) {
  int t    = blockIdx.x * 4 + (threadIdx.x >> 6);
  int lane = threadIdx.x & 63;
  const float* xr = x + (size_t)t * DIMK;
  float acc[NEXP];
#pragma unroll
  for (int e = 0; e < NEXP; ++e) acc[e] = 0.f;
  for (int i = lane; i < DIMK; i += 64) {
    float xv = xr[i];
#pragma unroll
    for (int e = 0; e < NEXP; ++e) acc[e] += xv * gw[e * DIMK + i];
  }
#pragma unroll
  for (int e = 0; e < NEXP; ++e) {
    float v = acc[e];
#pragma unroll
    for (int off = 32; off > 0; off >>= 1) v += __shfl_down(v, off, 64);
    acc[e] = v;
  }
  if (lane == 0) {
    float lg[NEXP];
#pragma unroll
    for (int e = 0; e < NEXP; ++e) lg[e] = acc[e] + gb[e];
    int i0 = 0;
#pragma unroll
    for (int e = 1; e < NEXP; ++e) if (lg[e] > lg[i0]) i0 = e;   // first index wins ties
    int i1 = (i0 == 0) ? 1 : 0;
#pragma unroll
    for (int e = 0; e < NEXP; ++e) if (e != i0 && lg[e] > lg[i1]) i1 = e;
    float mx = lg[i0], s = 0.f;
#pragma unroll
    for (int e = 0; e < NEXP; ++e) s += expf(lg[e] - mx);
    top_i[t * 2]     = i0;
    top_i[t * 2 + 1] = i1;
    top_w[t * 2]     = expf(lg[i0] - mx) / s;
    top_w[t * 2 + 1] = expf(lg[i1] - mx) / s;
  }
}

// ---------------- route_build: count + scan + slot-assign, deterministic ----------
__global__ __launch_bounds__(512) void route_build_kernel(
    const int* __restrict__ top_i, int* __restrict__ order, int* __restrict__ pos,
    int* __restrict__ poff_g) {
  __shared__ int cnt[NEXP][512];
  __shared__ int base[NEXP][512];
  __shared__ int totals[NEXP];
  __shared__ int poff_s[NEXP + 1];
  int tid = threadIdx.x;
  int lane = tid & 63, w = tid >> 6;
  const int t0 = tid * 16;

  int c[NEXP];
#pragma unroll
  for (int e = 0; e < NEXP; ++e) c[e] = 0;
  for (int j = 0; j < 16; ++j) {
    int e0 = top_i[(t0 + j) * 2];
    int e1 = top_i[(t0 + j) * 2 + 1];
#pragma unroll
    for (int e = 0; e < NEXP; ++e) c[e] += (e0 == e) + (e1 == e);
  }
#pragma unroll
  for (int e = 0; e < NEXP; ++e) cnt[e][tid] = c[e];
  __syncthreads();

  {
    int running = 0;
    for (int ch = 0; ch < 8; ++ch) {
      int v = cnt[w][ch * 64 + lane];
      int incl = v;
#pragma unroll
      for (int off = 1; off < 64; off <<= 1) {
        int u = __shfl_up(incl, off, 64);
        if (lane >= off) incl += u;
      }
      base[w][ch * 64 + lane] = running + incl - v;
      running += __shfl(incl, 63, 64);
    }
    if (lane == 0) totals[w] = running;
  }
  __syncthreads();

  if (tid == 0) {
    int off = 0;
#pragma unroll
    for (int e = 0; e < NEXP; ++e) {
      poff_s[e] = off;
      off += (totals[e] + 255) & ~255;
    }
    poff_s[NEXP] = off;
#pragma unroll
    for (int e = 0; e <= NEXP; ++e) poff_g[e] = poff_s[e];
  }
  __syncthreads();

  int cur[NEXP];
#pragma unroll
  for (int e = 0; e < NEXP; ++e) cur[e] = poff_s[e] + base[e][tid];
  for (int j = 0; j < 16; ++j) {
    int t = t0 + j;
#pragma unroll
    for (int k = 0; k < 2; ++k) {
      int ei = top_i[t * 2 + k];
      int p = 0;
#pragma unroll
      for (int e = 0; e < NEXP; ++e)
        if (ei == e) { p = cur[e]; cur[e] = p + 1; }
      order[p]       = t;
      pos[t * 2 + k] = p;
    }
  }

#pragma unroll
  for (int e = 0; e < NEXP; ++e) {
    int s = poff_s[e] + totals[e], en = poff_s[e + 1];
    for (int i = s + tid; i < en; i += 512) order[i] = 0;
  }
}

// ---------------- pipelined GEMM: BM=256, BN=128, BK=64, 512 thr (8 waves 4x2) ----
// Depth-2 prefetch: 3 LDS buffers (144 KB), counted vmcnt(6) waits for loads issued
// one FULL tile earlier (cover > HBM latency). One raw barrier per K-tile.
// Grid: blockIdx.x = N-slice (fast-varying -> co-resident blocks share A rows in L2),
//       blockIdx.y = M row-tile.
// EPI 0: paired swiglu epilogue (interleaved w1/w3 B) -> bf16 H, real cols = BN/2
// EPI 1: bias -> bf16 out;  EPI 2: bias -> f32 out
#define A_ELE   16384   // 256*64 elements per A buffer
#define B_ELE   8192    // 128*64 elements per B buffer
#define BUF_ELE (A_ELE + B_ELE)
template <bool EXPERTS, bool GATHER, int EPI>
__global__ __launch_bounds__(512) void gemm256_kernel(
    const unsigned short* __restrict__ A, int lda,
    const int* __restrict__ order, const int* __restrict__ poff,
    const unsigned short* __restrict__ B,          // row-major [N][K], per-expert wstride
    const float* __restrict__ bias1, const float* __restrict__ bias3,
    size_t wstride, int bstride, int K,
    void* __restrict__ outp, int ldo) {
  __shared__ unsigned short lds[3 * BUF_ELE];   // 144 KiB

  int rowbase = blockIdx.y * 256;
  int expert  = 0;
  if (EXPERTS) {
    if (rowbase >= poff[NEXP]) return;
    while (expert < NEXP - 1 && rowbase >= poff[expert + 1]) ++expert;
  }
  const unsigned short* Be = B + (size_t)expert * wstride;

  int tid = threadIdx.x;
  int lane = tid & 63, wid = tid >> 6;
  int wr = wid >> 1, wc = wid & 1;            // 4 x 2 wave grid: 64 rows x 64 cols each
  int ncolbase = blockIdx.x * 128;

  // staging addresses (element offsets); source chunk pre-swizzled: sub = (g&7)^(row&7)
  size_t aoff[4], boff[2];
#pragma unroll
  for (int l = 0; l < 4; ++l) {
    int g = l * 512 + tid;
    int r = g >> 3;
    int sub = (g & 7) ^ (r & 7);
    int gr = GATHER ? order[rowbase + r] : (rowbase + r);
    aoff[l] = (size_t)gr * lda + (size_t)(sub * 8);
  }
#pragma unroll
  for (int l = 0; l < 2; ++l) {
    int g = l * 512 + tid;
    int r = g >> 3;
    int sub = (g & 7) ^ (r & 7);
    boff[l] = (size_t)(ncolbase + r) * K + (size_t)(sub * 8);
  }

  f32x4 acc[4][4];
#pragma unroll
  for (int m = 0; m < 4; ++m)
#pragma unroll
    for (int n = 0; n < 4; ++n) acc[m][n] = f32x4{0.f, 0.f, 0.f, 0.f};

  const int NT = K >> 6;

  // ---- prologue: stage tiles 0 and 1 (6 loads/thread each) ----
#pragma unroll
  for (int l = 0; l < 4; ++l)
    gload16(A + aoff[l], &lds[(size_t)(l * 512 + tid) * 8]);
#pragma unroll
  for (int l = 0; l < 2; ++l)
    gload16(Be + boff[l], &lds[A_ELE + (size_t)(l * 512 + tid) * 8]);
#pragma unroll
  for (int l = 0; l < 4; ++l)
    gload16(A + aoff[l] + 64, &lds[BUF_ELE + (size_t)(l * 512 + tid) * 8]);
#pragma unroll
  for (int l = 0; l < 2; ++l)
    gload16(Be + boff[l] + 64, &lds[BUF_ELE + A_ELE + (size_t)(l * 512 + tid) * 8]);

  unsigned int off_r = 0, off_m = BUF_ELE, off_w = 2 * BUF_ELE;

  for (int t = 0; t < NT; ++t) {
    // wait: tile t landed (t+1's 6 loads may stay in flight)
    if (t + 1 < NT) {
      asm volatile("s_waitcnt vmcnt(6)" ::: "memory");
    } else {
      asm volatile("s_waitcnt vmcnt(0)" ::: "memory");
    }
    asm volatile("s_waitcnt lgkmcnt(0)" ::: "memory");   // my t-1 LDS reads done
    barrier_nodrain();   // collective: tile t visible, buf[off_w] free of readers

    const unsigned short* Ab = &lds[off_r];
    const unsigned short* Bb = &lds[off_r + A_ELE];
    const bool stage = (t + 2 < NT);
    const int kb = (t + 2) << 6;

    // ---- half kk=0: ds_reads, then stage-issue (A), then MFMA ----
    {
      bf16x8 a[4], b[4];
#pragma unroll
      for (int m = 0; m < 4; ++m) {
        int ra = wr * 64 + m * 16 + (lane & 15);
        int sa = ((lane >> 4)) ^ (ra & 7);
        a[m] = *(const bf16x8*)&Ab[ra * 64 + sa * 8];
      }
#pragma unroll
      for (int n = 0; n < 4; ++n) {
        int rb = wc * 64 + n * 16 + (lane & 15);
        int sb = ((lane >> 4)) ^ (rb & 7);
        b[n] = *(const bf16x8*)&Bb[rb * 64 + sb * 8];
      }
      if (stage) {
#pragma unroll
        for (int l = 0; l < 4; ++l)
          gload16(A + aoff[l] + kb, &lds[off_w + (size_t)(l * 512 + tid) * 8]);
      }
      __builtin_amdgcn_s_setprio(1);
#pragma unroll
      for (int m = 0; m < 4; ++m)
#pragma unroll
        for (int n = 0; n < 4; ++n)
          acc[m][n] = __builtin_amdgcn_mfma_f32_16x16x32_bf16(a[m], b[n], acc[m][n], 0, 0, 0);
      __builtin_amdgcn_s_setprio(0);
    }
    // ---- half kk=1: ds_reads, then stage-issue (B), then MFMA ----
    {
      bf16x8 a[4], b[4];
#pragma unroll
      for (int m = 0; m < 4; ++m) {
        int ra = wr * 64 + m * 16 + (lane & 15);
        int sa = (4 + (lane >> 4)) ^ (ra & 7);
        a[m] = *(const bf16x8*)&Ab[ra * 64 + sa * 8];
      }
#pragma unroll
      for (int n = 0; n < 4; ++n) {
        int rb = wc * 64 + n * 16 + (lane & 15);
        int sb = (4 + (lane >> 4)) ^ (rb & 7);
        b[n] = *(const bf16x8*)&Bb[rb * 64 + sb * 8];
      }
      if (stage) {
#pragma unroll
        for (int l = 0; l < 2; ++l)
          gload16(Be + boff[l] + kb, &lds[off_w + A_ELE + (size_t)(l * 512 + tid) * 8]);
      }
      __builtin_amdgcn_s_setprio(1);
#pragma unroll
      for (int m = 0; m < 4; ++m)
#pragma unroll
        for (int n = 0; n < 4; ++n)
          acc[m][n] = __builtin_amdgcn_mfma_f32_16x16x32_bf16(a[m], b[n], acc[m][n], 0, 0, 0);
      __builtin_amdgcn_s_setprio(0);
    }

    // rotate buffers: r <- m <- w <- r
    unsigned int tmp = off_r; off_r = off_m; off_m = off_w; off_w = tmp;
  }

  if (EPI == 0) {
    // interleaved pairs: n even = w1 fragment, n odd = w3 fragment; real cols = BN/2
#pragma unroll
    for (int m = 0; m < 4; ++m)
#pragma unroll
      for (int np = 0; np < 2; ++np) {
        int realcol = (ncolbase >> 1) + wc * 32 + np * 16 + (lane & 15);
        float bb1 = bias1[bstride * expert + realcol];
        float bb3 = bias3[bstride * expert + realcol];
#pragma unroll
        for (int j = 0; j < 4; ++j) {
          int row  = rowbase + wr * 64 + m * 16 + (lane >> 4) * 4 + j;
          float a1 = acc[m][2 * np][j] + bb1;
          float a3 = acc[m][2 * np + 1][j] + bb3;
          float hv = (a1 / (1.f + __expf(-a1))) * a3;   // silu(a1)*a3
          ((unsigned short*)outp)[(size_t)row * ldo + realcol] = f2b(hv);
        }
      }
  } else {
#pragma unroll
    for (int m = 0; m < 4; ++m)
#pragma unroll
      for (int n = 0; n < 4; ++n) {
        int col  = ncolbase + wc * 64 + n * 16 + (lane & 15);
        float bb = bias1[bstride * expert + col];
#pragma unroll
        for (int j = 0; j < 4; ++j) {
          int row = rowbase + wr * 64 + m * 16 + (lane >> 4) * 4 + j;
          float v = acc[m][n][j] + bb;
          if (EPI == 2)
            ((float*)outp)[(size_t)row * ldo + col] = v;
          else
            ((unsigned short*)outp)[(size_t)row * ldo + col] = f2b(v);
        }
      }
  }
}

// ---------------- combine: out += w0*y[p0] + w1*y[p1] ----------------
__global__ __launch_bounds__(256) void combine_kernel(
    float* __restrict__ out, const unsigned short* __restrict__ y,
    const int* __restrict__ pos, const float* __restrict__ tw) {
  size_t idx = (size_t)blockIdx.x * 256 + threadIdx.x;
  if (idx >= (size_t)T_TOK * DIMK) return;
  int t = (int)(idx >> 10);
  int d = (int)(idx & 1023);
  int p0 = pos[t * 2], p1 = pos[t * 2 + 1];
  float w0 = tw[t * 2], w1 = tw[t * 2 + 1];
  out[idx] += w0 * b2f(y[(size_t)p0 * DIMK + d]) + w1 * b2f(y[(size_t)p1 * DIMK + d]);
}

// ---------------- launch ----------------
extern "C" void kernel_launch(void* const* d_in, const int* in_sizes, int n_in,
                              void* d_out, int out_size, void* d_ws, size_t ws_size,
                              hipStream_t stream) {
  const float* x   = (const float*)d_in[0];
  const float* gw  = (const float*)d_in[1];
  const float* gb  = (const float*)d_in[2];
  const float* w1  = (const float*)d_in[3];
  const float* b1  = (const float*)d_in[4];
  const float* w3  = (const float*)d_in[5];
  const float* b3  = (const float*)d_in[6];
  const float* w2  = (const float*)d_in[7];
  const float* b2  = (const float*)d_in[8];
  const float* ws1 = (const float*)d_in[9];
  const float* bs1 = (const float*)d_in[10];
  const float* ws3 = (const float*)d_in[11];
  const float* bs3 = (const float*)d_in[12];
  const float* ws2 = (const float*)d_in[13];
  const float* bs2 = (const float*)d_in[14];
  float* out = (float*)d_out;
  (void)in_sizes; (void)n_in; (void)out_size; (void)ws_size;

  char* p = (char*)d_ws;
  auto alloc = [&](size_t bytes) -> void* {
    void* r = (void*)p;
    p += (bytes + 255) & ~(size_t)255;
    return r;
  };
  unsigned short* xb    = (unsigned short*)alloc((size_t)T_TOK * DIMK * 2);
  unsigned short* w13r  = (unsigned short*)alloc((size_t)NEXP * 2 * INTERK * DIMK * 2);
  unsigned short* w2b   = (unsigned short*)alloc((size_t)NEXP * DIMK * INTERK * 2);
  unsigned short* w13s  = (unsigned short*)alloc((size_t)2 * SINT * DIMK * 2);
  unsigned short* ws2b  = (unsigned short*)alloc((size_t)DIMK * SINT * 2);
  unsigned short* h     = (unsigned short*)alloc((size_t)CAP * INTERK * 2);
  unsigned short* yb    = (unsigned short*)alloc((size_t)CAP * DIMK * 2);
  unsigned short* hs    = (unsigned short*)alloc((size_t)T_TOK * SINT * 2);
  int*   top_i  = (int*)alloc((size_t)T_TOK * 2 * 4);
  float* top_w  = (float*)alloc((size_t)T_TOK * 2 * 4);
  int*   pos    = (int*)alloc((size_t)T_TOK * 2 * 4);
  int*   order  = (int*)alloc((size_t)CAP * 4);
  int*   poff   = (int*)alloc(64);

  auto cvt = [&](const float* src, unsigned short* dst, size_t n) {
    int n4 = (int)(n / 4);
    cvt_kernel<<<(n4 + 255) / 256, 256, 0, stream>>>((const float4*)src, dst, n4);
  };
  cvt(x,   xb,   (size_t)T_TOK * DIMK);
  cvt(w2,  w2b,  (size_t)NEXP * DIMK * INTERK);
  cvt(ws2, ws2b, (size_t)DIMK * SINT);

  {  // routed w1/w3 -> interleaved w13r
    int n = NEXP * INTERK * (DIMK / 4);
    cvt_w13_kernel<INTERK, DIMK / 4><<<(2 * n + 255) / 256, 256, 0, stream>>>(
        (const float4*)w1, (const float4*)w3, w13r, n);
  }
  {  // shared ws1/ws3 -> interleaved w13s
    int n = SINT * (DIMK / 4);
    cvt_w13_kernel<SINT, DIMK / 4><<<(2 * n + 255) / 256, 256, 0, stream>>>(
        (const float4*)ws1, (const float4*)ws3, w13s, n);
  }

  gate_kernel<<<T_TOK / 4, 256, 0, stream>>>(x, gw, gb, top_i, top_w);
  route_build_kernel<<<1, 512, 0, stream>>>(top_i, order, pos, poff);

  // routed expert pipeline (grid: x = N-slices, y = M row-tiles)
  gemm256_kernel<true, true, 0><<<dim3((2 * INTERK) / 128, RT256), 512, 0, stream>>>(
      xb, DIMK, order, poff, w13r, b1, b3,
      (size_t)2 * INTERK * DIMK, INTERK, DIMK, h, INTERK);
  gemm256_kernel<true, false, 1><<<dim3(DIMK / 128, RT256), 512, 0, stream>>>(
      h, INTERK, (const int*)nullptr, poff, w2b, b2, (const float*)nullptr,
      (size_t)DIMK * INTERK, DIMK, INTERK, (void*)yb, DIMK);

  // shared expert pipeline (writes z straight into d_out)
  gemm256_kernel<false, false, 0><<<dim3((2 * SINT) / 128, T_TOK / 256), 512, 0, stream>>>(
      xb, DIMK, (const int*)nullptr, (const int*)nullptr, w13s, bs1, bs3,
      (size_t)0, 0, DIMK, hs, SINT);
  gemm256_kernel<false, false, 2><<<dim3(DIMK / 128, T_TOK / 256), 512, 0, stream>>>(
      hs, SINT, (const int*)nullptr, (const int*)nullptr, ws2b, bs2, (const float*)nullptr,
      (size_t)0, 0, SINT, (void*)out, DIMK);

  // out += routed combine
  combine_kernel<<<(T_TOK * DIMK) / 256, 256, 0, stream>>>(out, yb, pos, top_w);
}